// Round 1
// baseline (762.992 us; speedup 1.0000x reference)
//
#include <hip/hip_runtime.h>
#include <math.h>

#define NV 8192
#define NE 4096
#define DIN 512
#define DH 256
#define CAP_E 96
#define CAP_V 64

// ---------------- workspace layout (float offsets) ----------------
#define OFF_XH   0                       // V*DH fp32 (residual)
#define OFF_UB   (OFF_XH + NV*DH)        // V*DH bf16 (U = Xh@W^T)
#define OFF_YB   (OFF_UB + NV*DH/2)      // E*DH bf16
#define OFF_NCNT (OFF_YB + NE*DH/2)      // V ints
#define OFF_ECNT (OFF_NCNT + NV)         // E*16 ints (line-padded counters)
#define OFF_BAR  (OFF_ECNT + NE*16)      // 32 ints: grid barrier (cnt @0, gen @16)
#define OFF_EL   (OFF_BAR + 32)          // E*CAP_E ints
#define OFF_NL   (OFF_EL + NE*CAP_E)     // V*CAP_V ints
#define OFF_XHB  (OFF_NL + NV*CAP_V)     // V*DH bf16
#define OFF_WB   (OFF_XHB + NV*DH/2)     // 2 * DH*DH bf16 (W0b | W1b)

using bf16x8 = __attribute__((ext_vector_type(8))) short;
using f32x4  = __attribute__((ext_vector_type(4))) float;
using f32x4v = __attribute__((ext_vector_type(4))) float;

__device__ inline unsigned short f2bf(float f) {   // round-to-nearest-even
    union { float f; unsigned u; } v; v.f = f;
    unsigned r = v.u + 0x7FFF + ((v.u >> 16) & 1);
    return (unsigned short)(r >> 16);
}
__device__ inline float b2f(unsigned short s) {
    union { unsigned u; float f; } v; v.u = ((unsigned)s) << 16; return v.f;
}

// device-scope sense-reversing grid barrier (cg::grid.sync equivalent).
// acq_rel RMW chain on cnt + release publish of gen; per-block wbl2/inv comes
// from the AGENT-scope atomics, so plain stores before the barrier are visible
// cross-XCD after it.
__device__ inline void gsync(int* bar, int nblk) {
    __syncthreads();
    if (threadIdx.x == 0) {
        int g = __hip_atomic_load(&bar[16], __ATOMIC_RELAXED, __HIP_MEMORY_SCOPE_AGENT);
        int a = __hip_atomic_fetch_add(&bar[0], 1, __ATOMIC_ACQ_REL, __HIP_MEMORY_SCOPE_AGENT);
        if (a == nblk - 1) {
            __hip_atomic_store(&bar[0], 0, __ATOMIC_RELAXED, __HIP_MEMORY_SCOPE_AGENT);
            __hip_atomic_store(&bar[16], g + 1, __ATOMIC_RELEASE, __HIP_MEMORY_SCOPE_AGENT);
        } else {
            while (__hip_atomic_load(&bar[16], __ATOMIC_RELAXED, __HIP_MEMORY_SCOPE_AGENT) <= g)
                __builtin_amdgcn_s_sleep(1);
            (void)__hip_atomic_load(&bar[16], __ATOMIC_ACQUIRE, __HIP_MEMORY_SCOPE_AGENT);
        }
    }
    __syncthreads();
}

// one persistent cooperative kernel: stage A (scan H + proj GEMM + W->bf16),
// then 2x { U-GEMM | edge gather | node gather+LN }, then pool+classify.
// 7 grid barriers replace 8 kernel boundaries.
__global__ __launch_bounds__(256, 4) void hgnn_mega(
    const float* __restrict__ X, const float* __restrict__ H,
    const float* __restrict__ Wp, const float* __restrict__ W0,
    const float* __restrict__ W1, const float* __restrict__ g0,
    const float* __restrict__ b0, const float* __restrict__ g1,
    const float* __restrict__ b1, const float* __restrict__ Wc,
    const float* __restrict__ bc,
    float* __restrict__ Xh, unsigned short* __restrict__ Xhb,
    unsigned short* __restrict__ Ub, unsigned short* __restrict__ Yb,
    unsigned short* __restrict__ Wb,
    int* __restrict__ edge_cnt, int* __restrict__ node_cnt,
    int* __restrict__ edge_list, int* __restrict__ node_list,
    int* __restrict__ bar, float* __restrict__ out)
{
    __shared__ short smem_s[9216];   // 18 KB: proj As/Bs, later gather lists
    const int nblk = gridDim.x;
    const int bid = blockIdx.x, tid = threadIdx.x;
    const int w = tid >> 6, lane = tid & 63;

    // ======================= stage A =======================
    const int nproj = nblk >> 2;     // 1/4 of blocks: proj GEMM + W conversion
    if (bid < nproj) {
        short* As = smem_s;
        short* Bs = smem_s + 1024;
        const int K = DIN;
        const int swz = lane ^ ((lane >> 3) & 6);
        for (int bt = bid; bt < NV / 32; bt += nproj) {
            const int bm = bt * 32;
            float4 ar, br[8];
            ar = *(const float4*)(X + (size_t)(bm + (tid >> 3)) * K + ((tid & 7) << 2));
#pragma unroll
            for (int it = 0; it < 8; ++it) {
                int i = tid + it * 256;
                br[it] = *(const float4*)(Wp + (size_t)(i >> 3) * K + ((i & 7) << 2));
            }
            f32x4 acc[2][4];
#pragma unroll
            for (int mi = 0; mi < 2; ++mi)
#pragma unroll
                for (int ni = 0; ni < 4; ++ni) acc[mi][ni] = (f32x4){0.f, 0.f, 0.f, 0.f};
            for (int k0 = 0; k0 < K; k0 += 32) {
                __syncthreads();
                {
                    int row = tid >> 3, kk = (tid & 7) << 2;
                    int quad = kk >> 3, j = kk & 7;
                    int ln = (row & 15) + (quad << 4);
                    int pp = ln ^ ((ln >> 3) & 6);
                    ushort4 u = {f2bf(ar.x), f2bf(ar.y), f2bf(ar.z), f2bf(ar.w)};
                    *(ushort4*)&As[(row >> 4) * 512 + pp * 8 + j] = u;
                }
#pragma unroll
                for (int it = 0; it < 8; ++it) {
                    int i = tid + it * 256;
                    int row = i >> 3, kk = (i & 7) << 2;
                    int quad = kk >> 3, j = kk & 7;
                    int ln = (row & 15) + (quad << 4);
                    int pp = ln ^ ((ln >> 3) & 6);
                    float4 v = br[it];
                    ushort4 u = {f2bf(v.x), f2bf(v.y), f2bf(v.z), f2bf(v.w)};
                    *(ushort4*)&Bs[(row >> 4) * 512 + pp * 8 + j] = u;
                }
                __syncthreads();
                if (k0 + 32 < K) {
                    int kn = k0 + 32;
                    ar = *(const float4*)(X + (size_t)(bm + (tid >> 3)) * K + kn + ((tid & 7) << 2));
#pragma unroll
                    for (int it = 0; it < 8; ++it) {
                        int i = tid + it * 256;
                        br[it] = *(const float4*)(Wp + (size_t)(i >> 3) * K + kn + ((i & 7) << 2));
                    }
                }
                bf16x8 af[2], bfr[4];
                af[0] = *(const bf16x8*)&As[0 * 512 + swz * 8];
                af[1] = *(const bf16x8*)&As[1 * 512 + swz * 8];
#pragma unroll
                for (int ni = 0; ni < 4; ++ni)
                    bfr[ni] = *(const bf16x8*)&Bs[(w * 4 + ni) * 512 + swz * 8];
#pragma unroll
                for (int mi = 0; mi < 2; ++mi)
#pragma unroll
                    for (int ni = 0; ni < 4; ++ni)
                        acc[mi][ni] = __builtin_amdgcn_mfma_f32_16x16x32_bf16(
                            af[mi], bfr[ni], acc[mi][ni], 0, 0, 0);
            }
            const int quad = lane >> 4, cl = lane & 15;
#pragma unroll
            for (int mi = 0; mi < 2; ++mi)
#pragma unroll
                for (int ni = 0; ni < 4; ++ni)
#pragma unroll
                    for (int r = 0; r < 4; ++r) {
                        float v = acc[mi][ni][r];
                        size_t idx = (size_t)(bm + mi * 16 + quad * 4 + r) * DH + w * 64 + ni * 16 + cl;
                        Xh[idx] = v;
                        Xhb[idx] = f2bf(v);
                    }
        }
        // one-shot W0/W1 -> bf16 (read once per launch instead of per GEMM block)
        for (int idx = bid * 256 + tid; idx < 2 * DH * DH / 4; idx += nproj * 256) {
            const float4* s4 = (const float4*)(idx < DH * DH / 4 ? W0 : W1);
            float4 v = s4[idx & (DH * DH / 4 - 1)];
            ushort4 u = {f2bf(v.x), f2bf(v.y), f2bf(v.z), f2bf(v.w)};
            ((ushort4*)Wb)[idx] = u;
        }
    } else {
        // scan H: wave-per-half-row, grid-stride, non-temporal loads
        const int sw0 = (bid - nproj) * 4 + w;
        const int nsw = (nblk - nproj) * 4;
        for (int hr = sw0; hr < NV * 2; hr += nsw) {
            const int v = hr >> 1, half = hr & 1;
            const f32x4v* H4 = (const f32x4v*)(H + (size_t)v * NE) + half * 512;
            f32x4v h[8];
#pragma unroll
            for (int it = 0; it < 8; ++it)
                h[it] = __builtin_nontemporal_load(&H4[lane + 64 * it]);
            unsigned m = 0u;
#pragma unroll
            for (int it = 0; it < 8; ++it) {
#pragma unroll
                for (int c = 0; c < 4; ++c)
                    m |= (h[it][c] != 0.0f ? 1u : 0u) << (it * 4 + c);
            }
            int n = __builtin_popcount(m);
            int pre = n;
#pragma unroll
            for (int o = 1; o < 64; o <<= 1) {
                int t = __shfl_up(pre, o, 64);
                if (lane >= o) pre += t;
            }
            int total = __shfl(pre, 63, 64);
            int local = pre - n;
            int base = 0;
            if (lane == 0 && total > 0) base = atomicAdd(&node_cnt[v], total);
            base = __shfl(base, 0, 64) + local;
            const int ebase = half * 2048 + 4 * lane;
            int e_arr[4] = {0, 0, 0, 0};
            {
                unsigned mm = m;
#pragma unroll
                for (int u = 0; u < 4; ++u) {
                    if (mm) {
                        int j = __builtin_ctz(mm);
                        mm &= mm - 1;
                        e_arr[u] = ebase + 256 * (j >> 2) + (j & 3);
                    }
                }
            }
            int s_arr[4];
#pragma unroll
            for (int u = 0; u < 4; ++u)
                s_arr[u] = (u < n) ? atomicAdd(&edge_cnt[e_arr[u] << 4], 1) : 0;
#pragma unroll
            for (int u = 0; u < 4; ++u) {
                if (u < n) {
                    if (s_arr[u] < CAP_E) edge_list[e_arr[u] * CAP_E + s_arr[u]] = v;
                    int idx = base + u;
                    if (idx < CAP_V) node_list[v * CAP_V + idx] = e_arr[u];
                }
            }
            if (n > 4) {
                unsigned mm = m;
                mm &= mm - 1; mm &= mm - 1; mm &= mm - 1; mm &= mm - 1;
                int k = 4;
                while (mm) {
                    int j = __builtin_ctz(mm); mm &= mm - 1;
                    int ee = ebase + 256 * (j >> 2) + (j & 3);
                    int gc = atomicAdd(&edge_cnt[ee << 4], 1);
                    if (gc < CAP_E) edge_list[ee * CAP_E + gc] = v;
                    int idx = base + k;
                    if (idx < CAP_V) node_list[v * CAP_V + idx] = ee;
                    ++k;
                }
            }
        }
    }
    gsync(bar, nblk);            // S0: lists + Xh/Xhb + Wb ready

    // ======================= 2 message-passing layers =======================
    for (int l = 0; l < 2; ++l) {
        const unsigned short* Wl = Wb + (size_t)l * DH * DH;
        const float* gg = l ? g1 : g0;
        const float* bb = l ? b1 : b0;

        // ---- U = bf16(Xhb @ Wl^T): LDS-free direct-fragment MFMA, BM=16 ----
        // A-frag: lane holds A[l&15][(l>>4)*8 + j] = 16B contiguous in row-major Xhb.
        // B-frag: lane holds B[k][l&15] = W[l&15-row][k..k+7] = 16B contiguous in Wl.
        {
            const int r15 = lane & 15, k8 = (lane >> 4) << 3;
            for (int t = bid; t < NV / 16; t += nblk) {
                const int bm = t * 16;
                f32x4 acc[4];
#pragma unroll
                for (int ni = 0; ni < 4; ++ni) acc[ni] = (f32x4){0.f, 0.f, 0.f, 0.f};
                const unsigned short* Ap = Xhb + (size_t)(bm + r15) * DH + k8;
                const unsigned short* Bp = Wl + (size_t)(w * 64 + r15) * DH + k8;
#pragma unroll
                for (int k0 = 0; k0 < DH; k0 += 32) {
                    bf16x8 a = *(const bf16x8*)(Ap + k0);
#pragma unroll
                    for (int ni = 0; ni < 4; ++ni) {
                        bf16x8 bfr = *(const bf16x8*)(Bp + (size_t)ni * 16 * DH + k0);
                        acc[ni] = __builtin_amdgcn_mfma_f32_16x16x32_bf16(a, bfr, acc[ni], 0, 0, 0);
                    }
                }
                const int quad = lane >> 4, cl = lane & 15;
#pragma unroll
                for (int ni = 0; ni < 4; ++ni)
#pragma unroll
                    for (int r = 0; r < 4; ++r)
                        Ub[(size_t)(bm + quad * 4 + r) * DH + w * 64 + ni * 16 + cl]
                            = f2bf(acc[ni][r]);
            }
        }
        gsync(bar, nblk);        // S1/S4: U ready

        // ---- edge gather: Yb[e] = bf16(rsqrt(de) * sum rsqrt(dv)*U[v]) ----
        {
            int* lvp = (int*)smem_s + w * 192;
            float* lcp = (float*)((int*)smem_s + w * 192 + 96);
            const int step = nblk * 4;
            const int trips = (NE + step - 1) / step;
            for (int tr = 0; tr < trips; ++tr) {
                const int e = bid * 4 + w + tr * step;
                const bool act = e < NE;
                int tc = 0, cnt = 0;
                if (act) {
                    tc = edge_cnt[e << 4];
                    cnt = min(tc, CAP_E);
                    for (int j = lane; j < cnt; j += 64) {
                        int v = edge_list[e * CAP_E + j];
                        lvp[j] = v * (DH / 4);
                        lcp[j] = rsqrtf((float)node_cnt[v]);
                    }
                }
                __syncthreads();
                if (act) {
                    const ushort4* X4 = (const ushort4*)Ub;
                    float4 a[8];
#pragma unroll
                    for (int u = 0; u < 8; ++u) a[u] = (float4){0.f, 0.f, 0.f, 0.f};
                    int i = 0;
                    for (; i + 8 <= cnt; i += 8) {
#pragma unroll
                        for (int u = 0; u < 8; ++u) {
                            ushort4 h = X4[lvp[i + u] + lane]; float c = lcp[i + u];
                            a[u].x = fmaf(c, b2f(h.x), a[u].x); a[u].y = fmaf(c, b2f(h.y), a[u].y);
                            a[u].z = fmaf(c, b2f(h.z), a[u].z); a[u].w = fmaf(c, b2f(h.w), a[u].w);
                        }
                    }
                    for (; i < cnt; ++i) {
                        ushort4 h = X4[lvp[i] + lane]; float c = lcp[i];
                        a[0].x = fmaf(c, b2f(h.x), a[0].x); a[0].y = fmaf(c, b2f(h.y), a[0].y);
                        a[0].z = fmaf(c, b2f(h.z), a[0].z); a[0].w = fmaf(c, b2f(h.w), a[0].w);
                    }
#pragma unroll
                    for (int u = 4; u > 0; u >>= 1)
#pragma unroll
                        for (int q = 0; q < u; ++q) {
                            a[q].x += a[q + u].x; a[q].y += a[q + u].y;
                            a[q].z += a[q + u].z; a[q].w += a[q + u].w;
                        }
                    float de = tc > 0 ? rsqrtf((float)tc) : 0.f;
                    ushort4 o = {f2bf(de * a[0].x), f2bf(de * a[0].y),
                                 f2bf(de * a[0].z), f2bf(de * a[0].w)};
                    ((ushort4*)Yb)[e * (DH / 4) + lane] = o;
                }
                __syncthreads();
            }
        }
        gsync(bar, nblk);        // S2/S5: Yb ready

        // ---- node gather + relu + residual + LayerNorm, wave per row ----
        {
            int* lep = (int*)smem_s + w * 128;
            float* lcp = (float*)((int*)smem_s + w * 128 + 64);
            const int step = nblk * 4;
            const int trips = (NV + step - 1) / step;
            for (int tr = 0; tr < trips; ++tr) {
                const int v = bid * 4 + w + tr * step;
                const bool act = v < NV;
                int tc = 0, cnt = 0;
                if (act) {
                    tc = node_cnt[v];
                    cnt = min(tc, CAP_V);
                    if (lane < cnt) {
                        int e = node_list[v * CAP_V + lane];
                        lep[lane] = e * (DH / 4);
                        lcp[lane] = rsqrtf((float)edge_cnt[e << 4]);
                    }
                }
                __syncthreads();
                if (act) {
                    const ushort4* Y4 = (const ushort4*)Yb;
                    float4 a[8];
#pragma unroll
                    for (int u = 0; u < 8; ++u) a[u] = (float4){0.f, 0.f, 0.f, 0.f};
                    int i = 0;
                    for (; i + 8 <= cnt; i += 8) {
#pragma unroll
                        for (int u = 0; u < 8; ++u) {
                            ushort4 h = Y4[lep[i + u] + lane]; float c = lcp[i + u];
                            a[u].x = fmaf(c, b2f(h.x), a[u].x); a[u].y = fmaf(c, b2f(h.y), a[u].y);
                            a[u].z = fmaf(c, b2f(h.z), a[u].z); a[u].w = fmaf(c, b2f(h.w), a[u].w);
                        }
                    }
                    for (; i < cnt; ++i) {
                        ushort4 h = Y4[lep[i] + lane]; float c = lcp[i];
                        a[0].x = fmaf(c, b2f(h.x), a[0].x); a[0].y = fmaf(c, b2f(h.y), a[0].y);
                        a[0].z = fmaf(c, b2f(h.z), a[0].z); a[0].w = fmaf(c, b2f(h.w), a[0].w);
                    }
#pragma unroll
                    for (int u = 4; u > 0; u >>= 1)
#pragma unroll
                        for (int q = 0; q < u; ++q) {
                            a[q].x += a[q + u].x; a[q].y += a[q + u].y;
                            a[q].z += a[q + u].z; a[q].w += a[q + u].w;
                        }
                    float dv = tc > 0 ? rsqrtf((float)tc) : 0.f;
                    float4 xr = ((const float4*)Xh)[v * (DH / 4) + lane];
                    float x0 = xr.x + fmaxf(dv * a[0].x, 0.f);
                    float x1 = xr.y + fmaxf(dv * a[0].y, 0.f);
                    float x2 = xr.z + fmaxf(dv * a[0].z, 0.f);
                    float x3 = xr.w + fmaxf(dv * a[0].w, 0.f);
                    float s = (x0 + x1) + (x2 + x3);
                    float q = fmaf(x0, x0, fmaf(x1, x1, fmaf(x2, x2, x3 * x3)));
#pragma unroll
                    for (int o = 1; o < 64; o <<= 1) {
                        s += __shfl_xor(s, o, 64);
                        q += __shfl_xor(q, o, 64);
                    }
                    float m = s * (1.0f / DH);
                    float var = q * (1.0f / DH) - m * m;
                    float rstd = rsqrtf(var + 1e-5f);
                    float4 g4 = ((const float4*)gg)[lane];
                    float4 b4 = ((const float4*)bb)[lane];
                    float4 o;
                    o.x = (x0 - m) * rstd * g4.x + b4.x;
                    o.y = (x1 - m) * rstd * g4.y + b4.y;
                    o.z = (x2 - m) * rstd * g4.z + b4.z;
                    o.w = (x3 - m) * rstd * g4.w + b4.w;
                    ((float4*)Xh)[v * (DH / 4) + lane] = o;
                    ushort4 ob = {f2bf(o.x), f2bf(o.y), f2bf(o.z), f2bf(o.w)};
                    ((ushort4*)Xhb)[v * (DH / 4) + lane] = ob;
                }
                __syncthreads();
            }
        }
        gsync(bar, nblk);        // S3/S6: Xh/Xhb updated
    }

    // ======================= pool + classify + softmax =======================
    {
        int* lvp = (int*)smem_s + w * 96;
        const int step = nblk * 4;
        const int trips = (NE + step - 1) / step;
        for (int tr = 0; tr < trips; ++tr) {
            const int e = bid * 4 + w + tr * step;
            const bool act = e < NE;
            int tc = 0, cnt = 0;
            if (act) {
                tc = edge_cnt[e << 4];
                cnt = min(tc, CAP_E);
                for (int j = lane; j < cnt; j += 64)
                    lvp[j] = edge_list[e * CAP_E + j] * (DH / 4);
            }
            __syncthreads();
            if (act) {
                const ushort4* X4 = (const ushort4*)Xhb;
                float4 a[8];
#pragma unroll
                for (int u = 0; u < 8; ++u) a[u] = (float4){0, 0, 0, 0};
                int i = 0;
                for (; i + 8 <= cnt; i += 8) {
#pragma unroll
                    for (int u = 0; u < 8; ++u) {
                        ushort4 h = X4[lvp[i + u] + lane];
                        a[u].x += b2f(h.x); a[u].y += b2f(h.y);
                        a[u].z += b2f(h.z); a[u].w += b2f(h.w);
                    }
                }
                for (; i < cnt; ++i) {
                    ushort4 h = X4[lvp[i] + lane];
                    a[0].x += b2f(h.x); a[0].y += b2f(h.y);
                    a[0].z += b2f(h.z); a[0].w += b2f(h.w);
                }
#pragma unroll
                for (int u = 4; u > 0; u >>= 1)
#pragma unroll
                    for (int q = 0; q < u; ++q) {
                        a[q].x += a[q + u].x; a[q].y += a[q + u].y;
                        a[q].z += a[q + u].z; a[q].w += a[q + u].w;
                    }
                float inv = tc > 0 ? 1.0f / (float)tc : 1.0f;
                float4 val = {a[0].x * inv, a[0].y * inv, a[0].z * inv, a[0].w * inv};
                const float4* W4 = (const float4*)Wc;
                float4 w0 = W4[lane], w1 = W4[64 + lane];
                float p0 = val.x * w0.x + val.y * w0.y + val.z * w0.z + val.w * w0.w;
                float p1 = val.x * w1.x + val.y * w1.y + val.z * w1.z + val.w * w1.w;
#pragma unroll
                for (int o = 32; o > 0; o >>= 1) {
                    p0 += __shfl_down(p0, o, 64);
                    p1 += __shfl_down(p1, o, 64);
                }
                if (lane == 0) {
                    float l0 = p0 + bc[0], l1 = p1 + bc[1];
                    float mx = fmaxf(l0, l1);
                    float e0 = expf(l0 - mx), e1 = expf(l1 - mx);
                    float sden = 1.0f / (e0 + e1);
                    out[e * 2 + 0] = e0 * sden;
                    out[e * 2 + 1] = e1 * sden;
                }
            }
            __syncthreads();
        }
    }
}

extern "C" void kernel_launch(void* const* d_in, const int* in_sizes, int n_in,
                              void* d_out, int out_size, void* d_ws, size_t ws_size,
                              hipStream_t stream) {
    const float* X  = (const float*)d_in[0];
    const float* H  = (const float*)d_in[1];
    const float* Wp = (const float*)d_in[2];
    const float* W0 = (const float*)d_in[3];
    const float* W1 = (const float*)d_in[4];
    const float* g0 = (const float*)d_in[5];
    const float* b0 = (const float*)d_in[6];
    const float* g1 = (const float*)d_in[7];
    const float* b1 = (const float*)d_in[8];
    const float* Wc = (const float*)d_in[9];
    const float* bc = (const float*)d_in[10];
    float* out = (float*)d_out;

    float* ws = (float*)d_ws;
    float* Xh  = ws + OFF_XH;
    unsigned short* Ub  = (unsigned short*)(ws + OFF_UB);
    unsigned short* Yb  = (unsigned short*)(ws + OFF_YB);
    int* node_cnt  = (int*)(ws + OFF_NCNT);
    int* edge_cnt  = (int*)(ws + OFF_ECNT);
    int* bar       = (int*)(ws + OFF_BAR);
    int* edge_list = (int*)(ws + OFF_EL);
    int* node_list = (int*)(ws + OFF_NL);
    unsigned short* Xhb = (unsigned short*)(ws + OFF_XHB);
    unsigned short* Wb  = (unsigned short*)(ws + OFF_WB);

    // pick a guaranteed-co-resident cooperative grid (cap 4 blocks/CU x 256 CUs)
    static int nblk = 0;
    if (nblk == 0) {
        int bpc = 0;
        if (hipOccupancyMaxActiveBlocksPerMultiprocessor(&bpc, hgnn_mega, 256, 0) != hipSuccess
            || bpc < 1)
            bpc = 2;
        if (bpc > 4) bpc = 4;
        nblk = bpc * 256;
    }

    // node_cnt, edge_cnt and the grid barrier are contiguous: one memset
    hipMemsetAsync(node_cnt, 0, (size_t)(NV + NE * 16 + 32) * sizeof(int), stream);

    void* args[] = {
        (void*)&X, (void*)&H, (void*)&Wp, (void*)&W0, (void*)&W1,
        (void*)&g0, (void*)&b0, (void*)&g1, (void*)&b1, (void*)&Wc, (void*)&bc,
        (void*)&Xh, (void*)&Xhb, (void*)&Ub, (void*)&Yb, (void*)&Wb,
        (void*)&edge_cnt, (void*)&node_cnt, (void*)&edge_list, (void*)&node_list,
        (void*)&bar, (void*)&out
    };
    hipLaunchCooperativeKernel((void*)hgnn_mega, dim3(nblk), dim3(256),
                               args, 0, stream);
}

// Round 2
// 578.647 us; speedup vs baseline: 1.3186x; 1.3186x over previous
//
#include <hip/hip_runtime.h>
#include <math.h>

#define NV 8192
#define NE 4096
#define DIN 512
#define DH 256
#define CAP_E 96
#define CAP_V 64

// ---------------- workspace layout (float offsets) ----------------
#define OFF_XH   0                       // V*DH fp32 (residual)
#define OFF_UB   (OFF_XH + NV*DH)        // V*DH bf16 (U = Xh@W^T)
#define OFF_YB   (OFF_UB + NV*DH/2)      // E*DH bf16
#define OFF_NCNT (OFF_YB + NE*DH/2)      // V ints
#define OFF_ECNT (OFF_NCNT + NV)         // E*16 ints (line-padded counters)
#define OFF_BAR  (OFF_ECNT + NE*16)      // 32 ints: grid barrier (cnt @0, gen @16)
#define OFF_EL   (OFF_BAR + 32)          // E*CAP_E ints
#define OFF_NL   (OFF_EL + NE*CAP_E)     // V*CAP_V ints
#define OFF_XHB  (OFF_NL + NV*CAP_V)     // V*DH bf16 (only for final pool)

using bf16x8 = __attribute__((ext_vector_type(8))) short;
using f32x4  = __attribute__((ext_vector_type(4))) float;
using f32x4v = __attribute__((ext_vector_type(4))) float;
typedef unsigned long long ull;

__device__ inline unsigned short f2bf(float f) {   // round-to-nearest-even
    union { float f; unsigned u; } v; v.f = f;
    unsigned r = v.u + 0x7FFF + ((v.u >> 16) & 1);
    return (unsigned short)(r >> 16);
}
__device__ inline float b2f(unsigned short s) {
    union { unsigned u; float f; } v; v.u = ((unsigned)s) << 16; return v.f;
}

// ---- cache-bypassing (agent-coherent, relaxed) accessors for intermediates.
// These lower to global_load/store with sc0 sc1: no L1/L2 allocation, served by
// the coherent LLC -> cross-XCD visible WITHOUT any wbl2/inv at barriers.
__device__ inline int  ld4i(const int* p) {
    return __hip_atomic_load(p, __ATOMIC_RELAXED, __HIP_MEMORY_SCOPE_AGENT);
}
__device__ inline void st4i(int* p, int v) {
    __hip_atomic_store(p, v, __ATOMIC_RELAXED, __HIP_MEMORY_SCOPE_AGENT);
}
__device__ inline void st4f(float* p, float v) {
    union { float f; unsigned u; } c; c.f = v;
    __hip_atomic_store((unsigned*)p, c.u, __ATOMIC_RELAXED, __HIP_MEMORY_SCOPE_AGENT);
}
__device__ inline ull ld8(const ull* p) {
    return __hip_atomic_load(p, __ATOMIC_RELAXED, __HIP_MEMORY_SCOPE_AGENT);
}
__device__ inline void st8(ull* p, ull v) {
    __hip_atomic_store(p, v, __ATOMIC_RELAXED, __HIP_MEMORY_SCOPE_AGENT);
}
union U64u { ull q; ushort4 h4; float2 f2; };

// fence-free grid barrier: intermediates bypass L1/L2, so no cache maintenance
// is needed. __syncthreads() drains vmcnt (stores reach LLC) before arrival.
__device__ inline void gsync(int* bar, int nblk) {
    __syncthreads();
    if (threadIdx.x == 0) {
        asm volatile("" ::: "memory");
        int g = __hip_atomic_load(&bar[16], __ATOMIC_RELAXED, __HIP_MEMORY_SCOPE_AGENT);
        int a = __hip_atomic_fetch_add(&bar[0], 1, __ATOMIC_RELAXED, __HIP_MEMORY_SCOPE_AGENT);
        if (a == nblk - 1) {
            __hip_atomic_store(&bar[0], 0, __ATOMIC_RELAXED, __HIP_MEMORY_SCOPE_AGENT);
            asm volatile("s_waitcnt vmcnt(0)" ::: "memory");   // reset visible before gen flip
            __hip_atomic_store(&bar[16], g + 1, __ATOMIC_RELAXED, __HIP_MEMORY_SCOPE_AGENT);
        } else {
            while (__hip_atomic_load(&bar[16], __ATOMIC_RELAXED, __HIP_MEMORY_SCOPE_AGENT) <= g)
                __builtin_amdgcn_s_sleep(2);
        }
        asm volatile("" ::: "memory");
    }
    __syncthreads();
}

__global__ __launch_bounds__(256, 4) void hgnn_mega(
    const float* __restrict__ X, const float* __restrict__ H,
    const float* __restrict__ Wp, const float* __restrict__ W0,
    const float* __restrict__ W1, const float* __restrict__ g0,
    const float* __restrict__ b0, const float* __restrict__ g1,
    const float* __restrict__ b1, const float* __restrict__ Wc,
    const float* __restrict__ bc,
    float* __restrict__ Xh, unsigned short* __restrict__ Xhb,
    unsigned short* __restrict__ Ub, unsigned short* __restrict__ Yb,
    int* __restrict__ edge_cnt, int* __restrict__ node_cnt,
    int* __restrict__ edge_list, int* __restrict__ node_list,
    int* __restrict__ bar, float* __restrict__ out)
{
    __shared__ __align__(16) short smem_s[9216];   // 18 KB
    const int nblk = gridDim.x;
    const int bid = blockIdx.x, tid = threadIdx.x;
    const int w = tid >> 6, lane = tid & 63;

    // ======================= stage A =======================
    const int nproj = nblk >> 2;     // 1/4 of blocks: proj GEMM
    if (bid < nproj) {
        short* As = smem_s;
        short* Bs = smem_s + 1024;
        const int K = DIN;
        const int swz = lane ^ ((lane >> 3) & 6);
        for (int bt = bid; bt < NV / 32; bt += nproj) {
            const int bm = bt * 32;
            float4 ar, br[8];
            ar = *(const float4*)(X + (size_t)(bm + (tid >> 3)) * K + ((tid & 7) << 2));
#pragma unroll
            for (int it = 0; it < 8; ++it) {
                int i = tid + it * 256;
                br[it] = *(const float4*)(Wp + (size_t)(i >> 3) * K + ((i & 7) << 2));
            }
            f32x4 acc[2][4];
#pragma unroll
            for (int mi = 0; mi < 2; ++mi)
#pragma unroll
                for (int ni = 0; ni < 4; ++ni) acc[mi][ni] = (f32x4){0.f, 0.f, 0.f, 0.f};
            for (int k0 = 0; k0 < K; k0 += 32) {
                __syncthreads();
                {
                    int row = tid >> 3, kk = (tid & 7) << 2;
                    int quad = kk >> 3, j = kk & 7;
                    int ln = (row & 15) + (quad << 4);
                    int pp = ln ^ ((ln >> 3) & 6);
                    ushort4 u = {f2bf(ar.x), f2bf(ar.y), f2bf(ar.z), f2bf(ar.w)};
                    *(ushort4*)&As[(row >> 4) * 512 + pp * 8 + j] = u;
                }
#pragma unroll
                for (int it = 0; it < 8; ++it) {
                    int i = tid + it * 256;
                    int row = i >> 3, kk = (i & 7) << 2;
                    int quad = kk >> 3, j = kk & 7;
                    int ln = (row & 15) + (quad << 4);
                    int pp = ln ^ ((ln >> 3) & 6);
                    float4 v = br[it];
                    ushort4 u = {f2bf(v.x), f2bf(v.y), f2bf(v.z), f2bf(v.w)};
                    *(ushort4*)&Bs[(row >> 4) * 512 + pp * 8 + j] = u;
                }
                __syncthreads();
                if (k0 + 32 < K) {
                    int kn = k0 + 32;
                    ar = *(const float4*)(X + (size_t)(bm + (tid >> 3)) * K + kn + ((tid & 7) << 2));
#pragma unroll
                    for (int it = 0; it < 8; ++it) {
                        int i = tid + it * 256;
                        br[it] = *(const float4*)(Wp + (size_t)(i >> 3) * K + kn + ((i & 7) << 2));
                    }
                }
                bf16x8 af[2], bfr[4];
                af[0] = *(const bf16x8*)&As[0 * 512 + swz * 8];
                af[1] = *(const bf16x8*)&As[1 * 512 + swz * 8];
#pragma unroll
                for (int ni = 0; ni < 4; ++ni)
                    bfr[ni] = *(const bf16x8*)&Bs[(w * 4 + ni) * 512 + swz * 8];
#pragma unroll
                for (int mi = 0; mi < 2; ++mi)
#pragma unroll
                    for (int ni = 0; ni < 4; ++ni)
                        acc[mi][ni] = __builtin_amdgcn_mfma_f32_16x16x32_bf16(
                            af[mi], bfr[ni], acc[mi][ni], 0, 0, 0);
            }
            const int quad = lane >> 4, cl = lane & 15;
#pragma unroll
            for (int mi = 0; mi < 2; ++mi)
#pragma unroll
                for (int ni = 0; ni < 4; ++ni)
#pragma unroll
                    for (int r = 0; r < 4; ++r) {
                        size_t idx = (size_t)(bm + mi * 16 + quad * 4 + r) * DH + w * 64 + ni * 16 + cl;
                        st4f(&Xh[idx], acc[mi][ni][r]);
                    }
        }
    } else {
        // scan H: wave-per-half-row, grid-stride, non-temporal loads
        const int sw0 = (bid - nproj) * 4 + w;
        const int nsw = (nblk - nproj) * 4;
        for (int hr = sw0; hr < NV * 2; hr += nsw) {
            const int v = hr >> 1, half = hr & 1;
            const f32x4v* H4 = (const f32x4v*)(H + (size_t)v * NE) + half * 512;
            f32x4v h[8];
#pragma unroll
            for (int it = 0; it < 8; ++it)
                h[it] = __builtin_nontemporal_load(&H4[lane + 64 * it]);
            unsigned m = 0u;
#pragma unroll
            for (int it = 0; it < 8; ++it) {
#pragma unroll
                for (int c = 0; c < 4; ++c)
                    m |= (h[it][c] != 0.0f ? 1u : 0u) << (it * 4 + c);
            }
            int n = __builtin_popcount(m);
            int pre = n;
#pragma unroll
            for (int o = 1; o < 64; o <<= 1) {
                int t = __shfl_up(pre, o, 64);
                if (lane >= o) pre += t;
            }
            int total = __shfl(pre, 63, 64);
            int local = pre - n;
            int base = 0;
            if (lane == 0 && total > 0) base = atomicAdd(&node_cnt[v], total);
            base = __shfl(base, 0, 64) + local;
            const int ebase = half * 2048 + 4 * lane;
            int e_arr[4] = {0, 0, 0, 0};
            {
                unsigned mm = m;
#pragma unroll
                for (int u = 0; u < 4; ++u) {
                    if (mm) {
                        int j = __builtin_ctz(mm);
                        mm &= mm - 1;
                        e_arr[u] = ebase + 256 * (j >> 2) + (j & 3);
                    }
                }
            }
            int s_arr[4];
#pragma unroll
            for (int u = 0; u < 4; ++u)
                s_arr[u] = (u < n) ? atomicAdd(&edge_cnt[e_arr[u] << 4], 1) : 0;
#pragma unroll
            for (int u = 0; u < 4; ++u) {
                if (u < n) {
                    if (s_arr[u] < CAP_E) st4i(&edge_list[e_arr[u] * CAP_E + s_arr[u]], v);
                    int idx = base + u;
                    if (idx < CAP_V) st4i(&node_list[v * CAP_V + idx], e_arr[u]);
                }
            }
            if (n > 4) {
                unsigned mm = m;
                mm &= mm - 1; mm &= mm - 1; mm &= mm - 1; mm &= mm - 1;
                int k = 4;
                while (mm) {
                    int j = __builtin_ctz(mm); mm &= mm - 1;
                    int ee = ebase + 256 * (j >> 2) + (j & 3);
                    int gc = atomicAdd(&edge_cnt[ee << 4], 1);
                    if (gc < CAP_E) st4i(&edge_list[ee * CAP_E + gc], v);
                    int idx = base + k;
                    if (idx < CAP_V) st4i(&node_list[v * CAP_V + idx], ee);
                    ++k;
                }
            }
        }
    }
    gsync(bar, nblk);            // S0: lists + Xh ready

    const ull* XhQ = (const ull*)Xh;
    ull* XhQw = (ull*)Xh;
    ull* UbQ = (ull*)Ub;
    const ull* UbQc = (const ull*)Ub;
    ull* YbQ = (ull*)Yb;
    const ull* YbQc = (const ull*)Yb;
    ull* XhbQ = (ull*)Xhb;
    const ull* XhbQc = (const ull*)Xhb;

    // ======================= 2 message-passing layers =======================
    for (int l = 0; l < 2; ++l) {
        const float* Wl = l ? W1 : W0;
        const float* gg = l ? g1 : g0;
        const float* bb = l ? b1 : b0;

        // ---- U = bf16(Xh @ Wl^T): LDS-free fragments, A from fp32 Xh (bypass),
        //      B from fp32 Wl (cached, read-only input), f2bf in-register.
        {
            const int r15 = lane & 15, k8 = (lane >> 4) << 3;
            const int ntile = NV / 16;
            const int trips = (ntile + nblk - 1) / nblk;
            for (int tt = 0; tt < trips; ++tt) {
                const int t = bid + tt * nblk;
                const bool act = t < ntile;          // block-uniform
                if (act) {
                    const int bm = t * 16;
                    f32x4 acc[4];
#pragma unroll
                    for (int ni = 0; ni < 4; ++ni) acc[ni] = (f32x4){0.f, 0.f, 0.f, 0.f};
                    const size_t arow = (size_t)(bm + r15) * (DH / 2);   // u64/row = 128
#pragma unroll 2
                    for (int k0 = 0; k0 < DH; k0 += 32) {
                        const int kq = (k8 + k0) >> 1;
                        U64u a0, a1, a2, a3;
                        a0.q = ld8(XhQ + arow + kq + 0);
                        a1.q = ld8(XhQ + arow + kq + 1);
                        a2.q = ld8(XhQ + arow + kq + 2);
                        a3.q = ld8(XhQ + arow + kq + 3);
                        bf16x8 av;
                        av[0] = (short)f2bf(a0.f2.x); av[1] = (short)f2bf(a0.f2.y);
                        av[2] = (short)f2bf(a1.f2.x); av[3] = (short)f2bf(a1.f2.y);
                        av[4] = (short)f2bf(a2.f2.x); av[5] = (short)f2bf(a2.f2.y);
                        av[6] = (short)f2bf(a3.f2.x); av[7] = (short)f2bf(a3.f2.y);
#pragma unroll
                        for (int ni = 0; ni < 4; ++ni) {
                            const float* wr = Wl + (size_t)(w * 64 + ni * 16 + r15) * DH + k8 + k0;
                            float4 bv0 = *(const float4*)wr;
                            float4 bv1 = *(const float4*)(wr + 4);
                            bf16x8 bv;
                            bv[0] = (short)f2bf(bv0.x); bv[1] = (short)f2bf(bv0.y);
                            bv[2] = (short)f2bf(bv0.z); bv[3] = (short)f2bf(bv0.w);
                            bv[4] = (short)f2bf(bv1.x); bv[5] = (short)f2bf(bv1.y);
                            bv[6] = (short)f2bf(bv1.z); bv[7] = (short)f2bf(bv1.w);
                            acc[ni] = __builtin_amdgcn_mfma_f32_16x16x32_bf16(av, bv, acc[ni], 0, 0, 0);
                        }
                    }
                    // epilogue: bounce through LDS (16x256 bf16 = 8KB), store 8B-aligned
                    const int quad = lane >> 4, cl = lane & 15;
#pragma unroll
                    for (int ni = 0; ni < 4; ++ni)
#pragma unroll
                        for (int r = 0; r < 4; ++r)
                            smem_s[(quad * 4 + r) * 256 + w * 64 + ni * 16 + cl]
                                = (short)f2bf(acc[ni][r]);
                    __syncthreads();
                    const ull* smQ = (const ull*)smem_s;
#pragma unroll
                    for (int c = 0; c < 4; ++c) {
                        int o = tid + c * 256;                 // u64 idx in tile [0,1024)
                        st8(UbQ + (size_t)bm * (DH / 4) + o, smQ[o]);
                    }
                }
            }
        }
        gsync(bar, nblk);        // S1/S4: U ready

        // ---- edge gather: Yb[e] = bf16(rsqrt(de) * sum rsqrt(dv)*U[v]) ----
        {
            int* lvp = (int*)smem_s + w * 192;
            float* lcp = (float*)((int*)smem_s + w * 192 + 96);
            const int step = nblk * 4;
            const int trips = (NE + step - 1) / step;
            for (int tr = 0; tr < trips; ++tr) {
                const int e = bid * 4 + w + tr * step;
                const bool act = e < NE;
                int tc = 0, cnt = 0;
                if (act) {
                    tc = ld4i(&edge_cnt[e << 4]);
                    cnt = min(tc, CAP_E);
                    for (int j = lane; j < cnt; j += 64) {
                        int v = ld4i(&edge_list[e * CAP_E + j]);
                        lvp[j] = v * (DH / 4);
                        lcp[j] = rsqrtf((float)ld4i(&node_cnt[v]));
                    }
                }
                __syncthreads();
                if (act) {
                    float4 a[8];
#pragma unroll
                    for (int u = 0; u < 8; ++u) a[u] = (float4){0.f, 0.f, 0.f, 0.f};
                    int i = 0;
                    for (; i + 8 <= cnt; i += 8) {
#pragma unroll
                        for (int u = 0; u < 8; ++u) {
                            U64u uu; uu.q = ld8(UbQc + lvp[i + u] + lane);
                            ushort4 h = uu.h4; float c = lcp[i + u];
                            a[u].x = fmaf(c, b2f(h.x), a[u].x); a[u].y = fmaf(c, b2f(h.y), a[u].y);
                            a[u].z = fmaf(c, b2f(h.z), a[u].z); a[u].w = fmaf(c, b2f(h.w), a[u].w);
                        }
                    }
                    for (; i < cnt; ++i) {
                        U64u uu; uu.q = ld8(UbQc + lvp[i] + lane);
                        ushort4 h = uu.h4; float c = lcp[i];
                        a[0].x = fmaf(c, b2f(h.x), a[0].x); a[0].y = fmaf(c, b2f(h.y), a[0].y);
                        a[0].z = fmaf(c, b2f(h.z), a[0].z); a[0].w = fmaf(c, b2f(h.w), a[0].w);
                    }
#pragma unroll
                    for (int u = 4; u > 0; u >>= 1)
#pragma unroll
                        for (int q = 0; q < u; ++q) {
                            a[q].x += a[q + u].x; a[q].y += a[q + u].y;
                            a[q].z += a[q + u].z; a[q].w += a[q + u].w;
                        }
                    float de = tc > 0 ? rsqrtf((float)tc) : 0.f;
                    ull qq = (ull)f2bf(de * a[0].x) | ((ull)f2bf(de * a[0].y) << 16)
                           | ((ull)f2bf(de * a[0].z) << 32) | ((ull)f2bf(de * a[0].w) << 48);
                    st8(YbQ + (size_t)e * (DH / 4) + lane, qq);
                }
                __syncthreads();
            }
        }
        gsync(bar, nblk);        // S2/S5: Yb ready

        // ---- node gather + relu + residual + LayerNorm, wave per row ----
        {
            int* lep = (int*)smem_s + w * 128;
            float* lcp = (float*)((int*)smem_s + w * 128 + 64);
            const int step = nblk * 4;
            const int trips = (NV + step - 1) / step;
            for (int tr = 0; tr < trips; ++tr) {
                const int v = bid * 4 + w + tr * step;
                const bool act = v < NV;
                int tc = 0, cnt = 0;
                if (act) {
                    tc = ld4i(&node_cnt[v]);
                    cnt = min(tc, CAP_V);
                    if (lane < cnt) {
                        int e = ld4i(&node_list[v * CAP_V + lane]);
                        lep[lane] = e * (DH / 4);
                        lcp[lane] = rsqrtf((float)ld4i(&edge_cnt[e << 4]));
                    }
                }
                __syncthreads();
                if (act) {
                    float4 a[8];
#pragma unroll
                    for (int u = 0; u < 8; ++u) a[u] = (float4){0.f, 0.f, 0.f, 0.f};
                    int i = 0;
                    for (; i + 8 <= cnt; i += 8) {
#pragma unroll
                        for (int u = 0; u < 8; ++u) {
                            U64u uu; uu.q = ld8(YbQc + lep[i + u] + lane);
                            ushort4 h = uu.h4; float c = lcp[i + u];
                            a[u].x = fmaf(c, b2f(h.x), a[u].x); a[u].y = fmaf(c, b2f(h.y), a[u].y);
                            a[u].z = fmaf(c, b2f(h.z), a[u].z); a[u].w = fmaf(c, b2f(h.w), a[u].w);
                        }
                    }
                    for (; i < cnt; ++i) {
                        U64u uu; uu.q = ld8(YbQc + lep[i] + lane);
                        ushort4 h = uu.h4; float c = lcp[i];
                        a[0].x = fmaf(c, b2f(h.x), a[0].x); a[0].y = fmaf(c, b2f(h.y), a[0].y);
                        a[0].z = fmaf(c, b2f(h.z), a[0].z); a[0].w = fmaf(c, b2f(h.w), a[0].w);
                    }
#pragma unroll
                    for (int u = 4; u > 0; u >>= 1)
#pragma unroll
                        for (int q = 0; q < u; ++q) {
                            a[q].x += a[q + u].x; a[q].y += a[q + u].y;
                            a[q].z += a[q + u].z; a[q].w += a[q + u].w;
                        }
                    float dv = tc > 0 ? rsqrtf((float)tc) : 0.f;
                    U64u x0, x1;
                    x0.q = ld8(XhQ + (size_t)v * (DH / 2) + lane * 2);
                    x1.q = ld8(XhQ + (size_t)v * (DH / 2) + lane * 2 + 1);
                    float xv0 = x0.f2.x + fmaxf(dv * a[0].x, 0.f);
                    float xv1 = x0.f2.y + fmaxf(dv * a[0].y, 0.f);
                    float xv2 = x1.f2.x + fmaxf(dv * a[0].z, 0.f);
                    float xv3 = x1.f2.y + fmaxf(dv * a[0].w, 0.f);
                    float s = (xv0 + xv1) + (xv2 + xv3);
                    float q = fmaf(xv0, xv0, fmaf(xv1, xv1, fmaf(xv2, xv2, xv3 * xv3)));
#pragma unroll
                    for (int o = 1; o < 64; o <<= 1) {
                        s += __shfl_xor(s, o, 64);
                        q += __shfl_xor(q, o, 64);
                    }
                    float m = s * (1.0f / DH);
                    float var = q * (1.0f / DH) - m * m;
                    float rstd = rsqrtf(var + 1e-5f);
                    float4 g4 = ((const float4*)gg)[lane];
                    float4 b4 = ((const float4*)bb)[lane];
                    float o0 = (xv0 - m) * rstd * g4.x + b4.x;
                    float o1 = (xv1 - m) * rstd * g4.y + b4.y;
                    float o2 = (xv2 - m) * rstd * g4.z + b4.z;
                    float o3 = (xv3 - m) * rstd * g4.w + b4.w;
                    U64u w0, w1; w0.f2.x = o0; w0.f2.y = o1; w1.f2.x = o2; w1.f2.y = o3;
                    st8(XhQw + (size_t)v * (DH / 2) + lane * 2, w0.q);
                    st8(XhQw + (size_t)v * (DH / 2) + lane * 2 + 1, w1.q);
                    if (l == 1) {
                        ull qq = (ull)f2bf(o0) | ((ull)f2bf(o1) << 16)
                               | ((ull)f2bf(o2) << 32) | ((ull)f2bf(o3) << 48);
                        st8(XhbQ + (size_t)v * (DH / 4) + lane, qq);
                    }
                }
                __syncthreads();
            }
        }
        gsync(bar, nblk);        // S3/S6: Xh (+Xhb on last layer) updated
    }

    // ======================= pool + classify + softmax =======================
    {
        int* lvp = (int*)smem_s + w * 96;
        const int step = nblk * 4;
        const int trips = (NE + step - 1) / step;
        for (int tr = 0; tr < trips; ++tr) {
            const int e = bid * 4 + w + tr * step;
            const bool act = e < NE;
            int tc = 0, cnt = 0;
            if (act) {
                tc = ld4i(&edge_cnt[e << 4]);
                cnt = min(tc, CAP_E);
                for (int j = lane; j < cnt; j += 64)
                    lvp[j] = ld4i(&edge_list[e * CAP_E + j]) * (DH / 4);
            }
            __syncthreads();
            if (act) {
                float4 a[8];
#pragma unroll
                for (int u = 0; u < 8; ++u) a[u] = (float4){0, 0, 0, 0};
                int i = 0;
                for (; i + 8 <= cnt; i += 8) {
#pragma unroll
                    for (int u = 0; u < 8; ++u) {
                        U64u uu; uu.q = ld8(XhbQc + lvp[i + u] + lane);
                        ushort4 h = uu.h4;
                        a[u].x += b2f(h.x); a[u].y += b2f(h.y);
                        a[u].z += b2f(h.z); a[u].w += b2f(h.w);
                    }
                }
                for (; i < cnt; ++i) {
                    U64u uu; uu.q = ld8(XhbQc + lvp[i] + lane);
                    ushort4 h = uu.h4;
                    a[0].x += b2f(h.x); a[0].y += b2f(h.y);
                    a[0].z += b2f(h.z); a[0].w += b2f(h.w);
                }
#pragma unroll
                for (int u = 4; u > 0; u >>= 1)
#pragma unroll
                    for (int q = 0; q < u; ++q) {
                        a[q].x += a[q + u].x; a[q].y += a[q + u].y;
                        a[q].z += a[q + u].z; a[q].w += a[q + u].w;
                    }
                float inv = tc > 0 ? 1.0f / (float)tc : 1.0f;
                float4 val = {a[0].x * inv, a[0].y * inv, a[0].z * inv, a[0].w * inv};
                const float4* W4 = (const float4*)Wc;
                float4 w0 = W4[lane], w1 = W4[64 + lane];
                float p0 = val.x * w0.x + val.y * w0.y + val.z * w0.z + val.w * w0.w;
                float p1 = val.x * w1.x + val.y * w1.y + val.z * w1.z + val.w * w1.w;
#pragma unroll
                for (int o = 32; o > 0; o >>= 1) {
                    p0 += __shfl_down(p0, o, 64);
                    p1 += __shfl_down(p1, o, 64);
                }
                if (lane == 0) {
                    float l0 = p0 + bc[0], l1 = p1 + bc[1];
                    float mx = fmaxf(l0, l1);
                    float e0 = expf(l0 - mx), e1 = expf(l1 - mx);
                    float sden = 1.0f / (e0 + e1);
                    out[e * 2 + 0] = e0 * sden;
                    out[e * 2 + 1] = e1 * sden;
                }
            }
            __syncthreads();
        }
    }
}

extern "C" void kernel_launch(void* const* d_in, const int* in_sizes, int n_in,
                              void* d_out, int out_size, void* d_ws, size_t ws_size,
                              hipStream_t stream) {
    const float* X  = (const float*)d_in[0];
    const float* H  = (const float*)d_in[1];
    const float* Wp = (const float*)d_in[2];
    const float* W0 = (const float*)d_in[3];
    const float* W1 = (const float*)d_in[4];
    const float* g0 = (const float*)d_in[5];
    const float* b0 = (const float*)d_in[6];
    const float* g1 = (const float*)d_in[7];
    const float* b1 = (const float*)d_in[8];
    const float* Wc = (const float*)d_in[9];
    const float* bc = (const float*)d_in[10];
    float* out = (float*)d_out;

    float* ws = (float*)d_ws;
    float* Xh  = ws + OFF_XH;
    unsigned short* Ub  = (unsigned short*)(ws + OFF_UB);
    unsigned short* Yb  = (unsigned short*)(ws + OFF_YB);
    int* node_cnt  = (int*)(ws + OFF_NCNT);
    int* edge_cnt  = (int*)(ws + OFF_ECNT);
    int* bar       = (int*)(ws + OFF_BAR);
    int* edge_list = (int*)(ws + OFF_EL);
    int* node_list = (int*)(ws + OFF_NL);
    unsigned short* Xhb = (unsigned short*)(ws + OFF_XHB);

    static int nblk = 0;
    if (nblk == 0) {
        int bpc = 0;
        if (hipOccupancyMaxActiveBlocksPerMultiprocessor(&bpc, hgnn_mega, 256, 0) != hipSuccess
            || bpc < 1)
            bpc = 2;
        if (bpc > 4) bpc = 4;
        nblk = bpc * 256;
    }

    // node_cnt, edge_cnt and the grid barrier are contiguous: one memset
    hipMemsetAsync(node_cnt, 0, (size_t)(NV + NE * 16 + 32) * sizeof(int), stream);

    void* args[] = {
        (void*)&X, (void*)&H, (void*)&Wp, (void*)&W0, (void*)&W1,
        (void*)&g0, (void*)&b0, (void*)&g1, (void*)&b1, (void*)&Wc, (void*)&bc,
        (void*)&Xh, (void*)&Xhb, (void*)&Ub, (void*)&Yb,
        (void*)&edge_cnt, (void*)&node_cnt, (void*)&edge_list, (void*)&node_list,
        (void*)&bar, (void*)&out
    };
    hipLaunchCooperativeKernel((void*)hgnn_mega, dim3(nblk), dim3(256),
                               args, 0, stream);
}

// Round 4
// 305.204 us; speedup vs baseline: 2.4999x; 1.8959x over previous
//
#include <hip/hip_runtime.h>
#include <math.h>

#define NV 8192
#define NE 4096
#define DIN 512
#define DH 256
#define CAP_E 96
#define CAP_V 64
#define NPROJ (NV / 32)      // 256 proj-GEMM blocks
#define NSCAN (NV / 2)       // 4096 scan blocks (4 waves/block, wave-per-half-row)

// ---------------- workspace layout (float offsets) ----------------
#define OFF_XH   0                       // V*DH fp32 (residual)
#define OFF_UB   (OFF_XH + NV*DH)        // V*DH bf16 (U = Xh@W^T)
#define OFF_YB   (OFF_UB + NV*DH/2)      // E*DH bf16
#define OFF_NCNT (OFF_YB + NE*DH/2)      // V ints
#define OFF_ECNT (OFF_NCNT + NV)         // E*16 ints (line-padded counters)
#define OFF_EL   (OFF_ECNT + NE*16)      // E*CAP_E ints
#define OFF_NL   (OFF_EL + NE*CAP_E)     // V*CAP_V ints
#define OFF_XHB  (OFF_NL + NV*CAP_V)     // V*DH bf16 (written by node_ln layer1, read by pool)

using bf16x8 = __attribute__((ext_vector_type(8))) short;
using f32x4  = __attribute__((ext_vector_type(4))) float;
using f32x4v = __attribute__((ext_vector_type(4))) float;

__device__ inline unsigned short f2bf(float f) {   // round-to-nearest-even
    union { float f; unsigned u; } v; v.f = f;
    unsigned r = v.u + 0x7FFF + ((v.u >> 16) & 1);
    return (unsigned short)(r >> 16);
}
__device__ inline float b2f(unsigned short s) {
    union { unsigned u; float f; } v; v.u = ((unsigned)s) << 16; return v.f;
}

// ---- U-GEMM from an LDS-stashed 32x256 bf16 A-tile: U = A @ W^T (bf16 out).
// A-tile layout: 16 sub-tiles of 512 shorts: (mi*8+kc)*512 + pp*8 + j where
// pp = ln ^ ((ln>>3)&6), ln = (row&15) + (kk>>3)*16, kk = col&31, kc = col>>5.
// B fragments read directly from fp32 W (L2-resident) with in-register f2bf —
// identical values to the old gemm_u's LDS-staged f2bf(W). K-chunk order
// ascending 32s => bit-identical accumulation to the old gemm_u.
__device__ inline void u_gemm_from_lds(const short* __restrict__ sm,
                                       const float* __restrict__ W,
                                       unsigned short* __restrict__ Ub,
                                       int bm, int tid) {
    const int w = tid >> 6, lane = tid & 63;
    const int r15 = lane & 15, k8 = (lane >> 4) << 3;
    const int swz = lane ^ ((lane >> 3) & 6);
    f32x4 acc[2][4];
#pragma unroll
    for (int mi = 0; mi < 2; ++mi)
#pragma unroll
        for (int ni = 0; ni < 4; ++ni) acc[mi][ni] = (f32x4){0.f, 0.f, 0.f, 0.f};
#pragma unroll
    for (int kc = 0; kc < 8; ++kc) {
        bf16x8 af[2], bfr[4];
        af[0] = *(const bf16x8*)&sm[(0 * 8 + kc) * 512 + swz * 8];
        af[1] = *(const bf16x8*)&sm[(1 * 8 + kc) * 512 + swz * 8];
#pragma unroll
        for (int ni = 0; ni < 4; ++ni) {
            const float* wr = W + (size_t)(w * 64 + ni * 16 + r15) * DH + kc * 32 + k8;
            float4 b0 = *(const float4*)wr;
            float4 b1 = *(const float4*)(wr + 4);
            bf16x8 bv;
            bv[0] = (short)f2bf(b0.x); bv[1] = (short)f2bf(b0.y);
            bv[2] = (short)f2bf(b0.z); bv[3] = (short)f2bf(b0.w);
            bv[4] = (short)f2bf(b1.x); bv[5] = (short)f2bf(b1.y);
            bv[6] = (short)f2bf(b1.z); bv[7] = (short)f2bf(b1.w);
            bfr[ni] = bv;
        }
#pragma unroll
        for (int mi = 0; mi < 2; ++mi)
#pragma unroll
            for (int ni = 0; ni < 4; ++ni)
                acc[mi][ni] = __builtin_amdgcn_mfma_f32_16x16x32_bf16(
                    af[mi], bfr[ni], acc[mi][ni], 0, 0, 0);
    }
    const int quad = lane >> 4, cl = lane & 15;
#pragma unroll
    for (int mi = 0; mi < 2; ++mi)
#pragma unroll
        for (int ni = 0; ni < 4; ++ni)
#pragma unroll
            for (int r = 0; r < 4; ++r)
                Ub[(size_t)(bm + mi * 16 + quad * 4 + r) * DH + w * 64 + ni * 16 + cl]
                    = f2bf(acc[mi][ni][r]);
}

// ---- fused: blocks [0,NPROJ) proj GEMM Xh = X @ Wp^T (BK=32) + U0 = tile @ W0^T;
//      blocks [NPROJ, NPROJ+NSCAN): scan H, wave-per-half-row, batched atomics. ----
__global__ __launch_bounds__(256) void scan_proj(const float* __restrict__ H,
                                                 const float* __restrict__ X,
                                                 const float* __restrict__ Wp,
                                                 const float* __restrict__ W0,
                                                 float* __restrict__ Xh,
                                                 unsigned short* __restrict__ Ub,
                                                 int* __restrict__ edge_cnt,
                                                 int* __restrict__ node_cnt,
                                                 int* __restrict__ edge_list,
                                                 int* __restrict__ node_list) {
    __shared__ short AsBs[1024 + 8192];
    const int tid = threadIdx.x;
    if (blockIdx.x >= NPROJ) {
        const int w = tid >> 6, lane = tid & 63;
        const int v    = (blockIdx.x - NPROJ) * 2 + (w >> 1);
        const int half = w & 1;
        const f32x4v* H4 = (const f32x4v*)(H + (size_t)v * NE) + half * 512;
        f32x4v h[8];
#pragma unroll
        for (int it = 0; it < 8; ++it)
            h[it] = __builtin_nontemporal_load(&H4[lane + 64 * it]);  // 8 indep 1KB nt loads
        unsigned m = 0u;
#pragma unroll
        for (int it = 0; it < 8; ++it) {
#pragma unroll
            for (int c = 0; c < 4; ++c)
                m |= (h[it][c] != 0.0f ? 1u : 0u) << (it * 4 + c);
        }
        int n = __builtin_popcount(m);
        int pre = n;
#pragma unroll
        for (int o = 1; o < 64; o <<= 1) {
            int t = __shfl_up(pre, o, 64);
            if (lane >= o) pre += t;
        }
        int total = __shfl(pre, 63, 64);
        int local = pre - n;
        int base = 0;
        if (lane == 0 && total > 0) base = atomicAdd(&node_cnt[v], total);
        base = __shfl(base, 0, 64) + local;
        const int ebase = half * 2048 + 4 * lane;
        int e_arr[4] = {0, 0, 0, 0};
        {
            unsigned mm = m;
#pragma unroll
            for (int u = 0; u < 4; ++u) {
                if (mm) {
                    int j = __builtin_ctz(mm);
                    mm &= mm - 1;
                    e_arr[u] = ebase + 256 * (j >> 2) + (j & 3);
                }
            }
        }
        int s_arr[4];
#pragma unroll
        for (int u = 0; u < 4; ++u)
            s_arr[u] = (u < n) ? atomicAdd(&edge_cnt[e_arr[u] << 4], 1) : 0;
#pragma unroll
        for (int u = 0; u < 4; ++u) {
            if (u < n) {
                if (s_arr[u] < CAP_E) edge_list[e_arr[u] * CAP_E + s_arr[u]] = v;
                int idx = base + u;
                if (idx < CAP_V) node_list[v * CAP_V + idx] = e_arr[u];
            }
        }
        if (n > 4) {
            unsigned mm = m;
            mm &= mm - 1; mm &= mm - 1; mm &= mm - 1; mm &= mm - 1;
            int k = 4;
            while (mm) {
                int j = __builtin_ctz(mm); mm &= mm - 1;
                int ee = ebase + 256 * (j >> 2) + (j & 3);
                int gc = atomicAdd(&edge_cnt[ee << 4], 1);
                if (gc < CAP_E) edge_list[ee * CAP_E + gc] = v;
                int idx = base + k;
                if (idx < CAP_V) node_list[v * CAP_V + idx] = ee;
                ++k;
            }
        }
        return;
    }
    // ---------------- proj GEMM path: BM=32, BN=256, BK=32, K=DIN ----------------
    short* As = AsBs;
    short* Bs = AsBs + 1024;
    const int K = DIN;
    const int lane = tid & 63;
    const int w    = tid >> 6;
    const int bm   = blockIdx.x * 32;
    const int swz  = lane ^ ((lane >> 3) & 6);
    float4 ar, br[8];
    ar = *(const float4*)(X + (size_t)(bm + (tid >> 3)) * K + ((tid & 7) << 2));
#pragma unroll
    for (int it = 0; it < 8; ++it) {
        int i = tid + it * 256;
        br[it] = *(const float4*)(Wp + (size_t)(i >> 3) * K + ((i & 7) << 2));
    }
    f32x4 acc[2][4];
#pragma unroll
    for (int mi = 0; mi < 2; ++mi)
#pragma unroll
        for (int ni = 0; ni < 4; ++ni) acc[mi][ni] = (f32x4){0.f, 0.f, 0.f, 0.f};
    for (int k0 = 0; k0 < K; k0 += 32) {
        __syncthreads();
        {
            int row = tid >> 3, kk = (tid & 7) << 2;
            int quad = kk >> 3, j = kk & 7;
            int ln = (row & 15) + (quad << 4);
            int pp = ln ^ ((ln >> 3) & 6);
            ushort4 u = {f2bf(ar.x), f2bf(ar.y), f2bf(ar.z), f2bf(ar.w)};
            *(ushort4*)&As[(row >> 4) * 512 + pp * 8 + j] = u;
        }
#pragma unroll
        for (int it = 0; it < 8; ++it) {
            int i = tid + it * 256;
            int row = i >> 3, kk = (i & 7) << 2;
            int quad = kk >> 3, j = kk & 7;
            int ln = (row & 15) + (quad << 4);
            int pp = ln ^ ((ln >> 3) & 6);
            float4 v = br[it];
            ushort4 u = {f2bf(v.x), f2bf(v.y), f2bf(v.z), f2bf(v.w)};
            *(ushort4*)&Bs[(row >> 4) * 512 + pp * 8 + j] = u;
        }
        __syncthreads();
        if (k0 + 32 < K) {
            int kn = k0 + 32;
            ar = *(const float4*)(X + (size_t)(bm + (tid >> 3)) * K + kn + ((tid & 7) << 2));
#pragma unroll
            for (int it = 0; it < 8; ++it) {
                int i = tid + it * 256;
                br[it] = *(const float4*)(Wp + (size_t)(i >> 3) * K + kn + ((i & 7) << 2));
            }
        }
        bf16x8 af[2], bfr[4];
        af[0] = *(const bf16x8*)&As[0 * 512 + swz * 8];
        af[1] = *(const bf16x8*)&As[1 * 512 + swz * 8];
#pragma unroll
        for (int ni = 0; ni < 4; ++ni)
            bfr[ni] = *(const bf16x8*)&Bs[(w * 4 + ni) * 512 + swz * 8];
#pragma unroll
        for (int mi = 0; mi < 2; ++mi)
#pragma unroll
            for (int ni = 0; ni < 4; ++ni)
                acc[mi][ni] = __builtin_amdgcn_mfma_f32_16x16x32_bf16(
                    af[mi], bfr[ni], acc[mi][ni], 0, 0, 0);
    }
    const int quad = lane >> 4, cl = lane & 15;
    __syncthreads();   // all waves done reading As/Bs before the U-stash reuses LDS
#pragma unroll
    for (int mi = 0; mi < 2; ++mi)
#pragma unroll
        for (int ni = 0; ni < 4; ++ni)
#pragma unroll
            for (int r = 0; r < 4; ++r) {
                float v = acc[mi][ni][r];
                int rl  = mi * 16 + quad * 4 + r;
                int col = w * 64 + ni * 16 + cl;
                Xh[(size_t)(bm + rl) * DH + col] = v;
                // stash bf16 into MFMA-ready swizzled A-tile for the fused U0-GEMM
                int kc = col >> 5, kk = col & 31;
                int q2 = kk >> 3, j = kk & 7;
                int ln = (rl & 15) + (q2 << 4);
                int pp = ln ^ ((ln >> 3) & 6);
                AsBs[(mi * 8 + kc) * 512 + pp * 8 + j] = (short)f2bf(v);
            }
    __syncthreads();
    u_gemm_from_lds(AsBs, W0, Ub, bm, tid);
}

// ---- Yb[e,:] = bf16( rsqrt(de) * sum_{v in e} rsqrt(dv) * Ub[v,:] ) ----
__global__ __launch_bounds__(64) void edge_gather(const unsigned short* __restrict__ Ub,
                                                  const int* __restrict__ edge_cnt,
                                                  const int* __restrict__ edge_list,
                                                  const int* __restrict__ node_cnt,
                                                  unsigned short* __restrict__ Yb) {
    int e = blockIdx.x;
    int tid = threadIdx.x;
    __shared__ int   lv[CAP_E];
    __shared__ float lc[CAP_E];
    int tc = edge_cnt[e << 4];
    int cnt = min(tc, CAP_E);
    for (int j = tid; j < cnt; j += 64) {
        int v = edge_list[e * CAP_E + j];
        lv[j] = v * (DH / 4);
        lc[j] = rsqrtf((float)node_cnt[v]);
    }
    __syncthreads();
    const ushort4* X4 = (const ushort4*)Ub;
    float4 a[8];
#pragma unroll
    for (int u = 0; u < 8; ++u) a[u] = (float4){0.f, 0.f, 0.f, 0.f};
    int i = 0;
    for (; i + 8 <= cnt; i += 8) {
#pragma unroll
        for (int u = 0; u < 8; ++u) {
            ushort4 h = X4[lv[i + u] + tid]; float c = lc[i + u];
            a[u].x = fmaf(c, b2f(h.x), a[u].x); a[u].y = fmaf(c, b2f(h.y), a[u].y);
            a[u].z = fmaf(c, b2f(h.z), a[u].z); a[u].w = fmaf(c, b2f(h.w), a[u].w);
        }
    }
    for (; i < cnt; ++i) {
        ushort4 h = X4[lv[i] + tid]; float c = lc[i];
        a[0].x = fmaf(c, b2f(h.x), a[0].x); a[0].y = fmaf(c, b2f(h.y), a[0].y);
        a[0].z = fmaf(c, b2f(h.z), a[0].z); a[0].w = fmaf(c, b2f(h.w), a[0].w);
    }
#pragma unroll
    for (int u = 4; u > 0; u >>= 1)
#pragma unroll
        for (int q = 0; q < u; ++q) {
            a[q].x += a[q + u].x; a[q].y += a[q + u].y;
            a[q].z += a[q + u].z; a[q].w += a[q + u].w;
        }
    float de = tc > 0 ? rsqrtf((float)tc) : 0.f;
    ushort4 o = {f2bf(de * a[0].x), f2bf(de * a[0].y),
                 f2bf(de * a[0].z), f2bf(de * a[0].w)};
    ((ushort4*)Yb)[e * (DH / 4) + tid] = o;
}

// ---- layer-0: node gather + relu + residual + LayerNorm + fused U1 = tile @ W1^T.
//      32 rows per block (4 waves x 8 sequential rows), identical per-row math
//      to node_ln; LN output stashed bf16 in LDS then MFMA'd against W1. ----
__global__ __launch_bounds__(256) void node_ln_u(const unsigned short* __restrict__ Yb,
                                                 const int* __restrict__ node_cnt,
                                                 const int* __restrict__ node_list,
                                                 const int* __restrict__ edge_cnt,
                                                 float* __restrict__ Xh,
                                                 const float* __restrict__ g,
                                                 const float* __restrict__ b,
                                                 const float* __restrict__ W1,
                                                 unsigned short* __restrict__ Ub) {
    __shared__ short sm[9216];            // [0,8192): A-tile; [8192,9216): 4x128 ints
    const int tid = threadIdx.x;
    const int w = tid >> 6, lane = tid & 63;
    const int bm = blockIdx.x * 32;
    int* lbase = (int*)&sm[8192];
    int*   lep = lbase + w * 128;
    float* lcp = (float*)(lbase + w * 128 + 64);
    for (int ii = 0; ii < 8; ++ii) {
        const int rl = ii * 4 + w;        // block-local row, disjoint per wave
        const int v  = bm + rl;
        int tc = node_cnt[v];
        int cnt = min(tc, CAP_V);
        if (lane < cnt) {
            int e = node_list[v * CAP_V + lane];
            lep[lane] = e * (DH / 4);
            lcp[lane] = rsqrtf((float)edge_cnt[e << 4]);
        }
        __syncthreads();
        const ushort4* Y4 = (const ushort4*)Yb;
        float4 a[8];
#pragma unroll
        for (int u = 0; u < 8; ++u) a[u] = (float4){0.f, 0.f, 0.f, 0.f};
        int i = 0;
        for (; i + 8 <= cnt; i += 8) {
#pragma unroll
            for (int u = 0; u < 8; ++u) {
                ushort4 h = Y4[lep[i + u] + lane]; float c = lcp[i + u];
                a[u].x = fmaf(c, b2f(h.x), a[u].x); a[u].y = fmaf(c, b2f(h.y), a[u].y);
                a[u].z = fmaf(c, b2f(h.z), a[u].z); a[u].w = fmaf(c, b2f(h.w), a[u].w);
            }
        }
        for (; i < cnt; ++i) {
            ushort4 h = Y4[lep[i] + lane]; float c = lcp[i];
            a[0].x = fmaf(c, b2f(h.x), a[0].x); a[0].y = fmaf(c, b2f(h.y), a[0].y);
            a[0].z = fmaf(c, b2f(h.z), a[0].z); a[0].w = fmaf(c, b2f(h.w), a[0].w);
        }
#pragma unroll
        for (int u = 4; u > 0; u >>= 1)
#pragma unroll
            for (int q = 0; q < u; ++q) {
                a[q].x += a[q + u].x; a[q].y += a[q + u].y;
                a[q].z += a[q + u].z; a[q].w += a[q + u].w;
            }
        float dv = tc > 0 ? rsqrtf((float)tc) : 0.f;
        float4 xr = ((const float4*)Xh)[v * (DH / 4) + lane];
        float x0 = xr.x + fmaxf(dv * a[0].x, 0.f);
        float x1 = xr.y + fmaxf(dv * a[0].y, 0.f);
        float x2 = xr.z + fmaxf(dv * a[0].z, 0.f);
        float x3 = xr.w + fmaxf(dv * a[0].w, 0.f);
        float s = (x0 + x1) + (x2 + x3);
        float q = fmaf(x0, x0, fmaf(x1, x1, fmaf(x2, x2, x3 * x3)));
#pragma unroll
        for (int o = 1; o < 64; o <<= 1) {
            s += __shfl_xor(s, o, 64);
            q += __shfl_xor(q, o, 64);
        }
        float m = s * (1.0f / DH);
        float var = q * (1.0f / DH) - m * m;
        float rstd = rsqrtf(var + 1e-5f);
        float4 g4 = ((const float4*)g)[lane];
        float4 b4 = ((const float4*)b)[lane];
        float4 o;
        o.x = (x0 - m) * rstd * g4.x + b4.x;
        o.y = (x1 - m) * rstd * g4.y + b4.y;
        o.z = (x2 - m) * rstd * g4.z + b4.z;
        o.w = (x3 - m) * rstd * g4.w + b4.w;
        ((float4*)Xh)[v * (DH / 4) + lane] = o;
        // stash bf16 row into the swizzled A-tile (cols 4*lane..4*lane+3)
        ushort4 ob = {f2bf(o.x), f2bf(o.y), f2bf(o.z), f2bf(o.w)};
        int mi = rl >> 4, kc = lane >> 3;
        int q2 = (lane & 7) >> 1, jj = (lane & 1) * 4;
        int ln = (rl & 15) + (q2 << 4);
        int pp = ln ^ ((ln >> 3) & 6);
        *(ushort4*)&sm[(mi * 8 + kc) * 512 + pp * 8 + jj] = ob;
        __syncthreads();
    }
    u_gemm_from_lds(sm, W1, Ub, bm, tid);
}

// ---- layer-1: node gather + relu + residual + LayerNorm (original, writes Xhb) ----
__global__ __launch_bounds__(64) void node_ln(const unsigned short* __restrict__ Yb,
                                              const int* __restrict__ node_cnt,
                                              const int* __restrict__ node_list,
                                              const int* __restrict__ edge_cnt,
                                              float* __restrict__ Xh,
                                              unsigned short* __restrict__ Xhb,
                                              const float* __restrict__ g,
                                              const float* __restrict__ b) {
    int v = blockIdx.x;
    int tid = threadIdx.x;
    __shared__ int   le[CAP_V];
    __shared__ float lc[CAP_V];
    int tc = node_cnt[v];
    int cnt = min(tc, CAP_V);
    if (tid < cnt) {
        int e = node_list[v * CAP_V + tid];
        le[tid] = e * (DH / 4);
        lc[tid] = rsqrtf((float)edge_cnt[e << 4]);
    }
    __syncthreads();
    const ushort4* Y4 = (const ushort4*)Yb;
    float4 a[8];
#pragma unroll
    for (int u = 0; u < 8; ++u) a[u] = (float4){0.f, 0.f, 0.f, 0.f};
    int i = 0;
    for (; i + 8 <= cnt; i += 8) {
#pragma unroll
        for (int u = 0; u < 8; ++u) {
            ushort4 h = Y4[le[i + u] + tid]; float c = lc[i + u];
            a[u].x = fmaf(c, b2f(h.x), a[u].x); a[u].y = fmaf(c, b2f(h.y), a[u].y);
            a[u].z = fmaf(c, b2f(h.z), a[u].z); a[u].w = fmaf(c, b2f(h.w), a[u].w);
        }
    }
    for (; i < cnt; ++i) {
        ushort4 h = Y4[le[i] + tid]; float c = lc[i];
        a[0].x = fmaf(c, b2f(h.x), a[0].x); a[0].y = fmaf(c, b2f(h.y), a[0].y);
        a[0].z = fmaf(c, b2f(h.z), a[0].z); a[0].w = fmaf(c, b2f(h.w), a[0].w);
    }
#pragma unroll
    for (int u = 4; u > 0; u >>= 1)
#pragma unroll
        for (int q = 0; q < u; ++q) {
            a[q].x += a[q + u].x; a[q].y += a[q + u].y;
            a[q].z += a[q + u].z; a[q].w += a[q + u].w;
        }
    float dv = tc > 0 ? rsqrtf((float)tc) : 0.f;
    float4 xr = ((const float4*)Xh)[v * (DH / 4) + tid];
    float x0 = xr.x + fmaxf(dv * a[0].x, 0.f);
    float x1 = xr.y + fmaxf(dv * a[0].y, 0.f);
    float x2 = xr.z + fmaxf(dv * a[0].z, 0.f);
    float x3 = xr.w + fmaxf(dv * a[0].w, 0.f);
    float s = (x0 + x1) + (x2 + x3);
    float q = fmaf(x0, x0, fmaf(x1, x1, fmaf(x2, x2, x3 * x3)));
#pragma unroll
    for (int o = 1; o < 64; o <<= 1) {
        s += __shfl_xor(s, o, 64);
        q += __shfl_xor(q, o, 64);
    }
    float m = s * (1.0f / DH);
    float var = q * (1.0f / DH) - m * m;
    float rstd = rsqrtf(var + 1e-5f);
    float4 g4 = ((const float4*)g)[tid];
    float4 b4 = ((const float4*)b)[tid];
    float4 o;
    o.x = (x0 - m) * rstd * g4.x + b4.x;
    o.y = (x1 - m) * rstd * g4.y + b4.y;
    o.z = (x2 - m) * rstd * g4.z + b4.z;
    o.w = (x3 - m) * rstd * g4.w + b4.w;
    ((float4*)Xh)[v * (DH / 4) + tid] = o;
    ushort4 ob = {f2bf(o.x), f2bf(o.y), f2bf(o.z), f2bf(o.w)};
    ((ushort4*)Xhb)[v * (DH / 4) + tid] = ob;
}

// ------- fused mean-pool + classifier + softmax (64 thr, bf16 src) -------
__global__ __launch_bounds__(64) void pool_classify(const unsigned short* __restrict__ Xhb,
                                                    const int* __restrict__ edge_cnt,
                                                    const int* __restrict__ edge_list,
                                                    const float* __restrict__ Wc,
                                                    const float* __restrict__ bc,
                                                    float* __restrict__ out) {
    int e = blockIdx.x;
    int tid = threadIdx.x;
    __shared__ int lv[CAP_E];
    int tc = edge_cnt[e << 4];
    int cnt = min(tc, CAP_E);
    for (int j = tid; j < cnt; j += 64) lv[j] = edge_list[e * CAP_E + j] * (DH / 4);
    __syncthreads();
    const ushort4* X4 = (const ushort4*)Xhb;
    float4 a[8];
#pragma unroll
    for (int u = 0; u < 8; ++u) a[u] = (float4){0, 0, 0, 0};
    int i = 0;
    for (; i + 8 <= cnt; i += 8) {
#pragma unroll
        for (int u = 0; u < 8; ++u) {
            ushort4 h = X4[lv[i + u] + tid];
            a[u].x += b2f(h.x); a[u].y += b2f(h.y);
            a[u].z += b2f(h.z); a[u].w += b2f(h.w);
        }
    }
    for (; i < cnt; ++i) {
        ushort4 h = X4[lv[i] + tid];
        a[0].x += b2f(h.x); a[0].y += b2f(h.y);
        a[0].z += b2f(h.z); a[0].w += b2f(h.w);
    }
#pragma unroll
    for (int u = 4; u > 0; u >>= 1)
#pragma unroll
        for (int q = 0; q < u; ++q) {
            a[q].x += a[q + u].x; a[q].y += a[q + u].y;
            a[q].z += a[q + u].z; a[q].w += a[q + u].w;
        }
    float inv = tc > 0 ? 1.0f / (float)tc : 1.0f;
    float4 val = {a[0].x * inv, a[0].y * inv, a[0].z * inv, a[0].w * inv};
    const float4* W4 = (const float4*)Wc;
    float4 w0 = W4[tid], w1 = W4[64 + tid];
    float p0 = val.x * w0.x + val.y * w0.y + val.z * w0.z + val.w * w0.w;
    float p1 = val.x * w1.x + val.y * w1.y + val.z * w1.z + val.w * w1.w;
#pragma unroll
    for (int o = 32; o > 0; o >>= 1) {
        p0 += __shfl_down(p0, o, 64);
        p1 += __shfl_down(p1, o, 64);
    }
    if (tid == 0) {
        float l0 = p0 + bc[0], l1 = p1 + bc[1];
        float mx = fmaxf(l0, l1);
        float e0 = expf(l0 - mx), e1 = expf(l1 - mx);
        float s = 1.0f / (e0 + e1);
        out[e * 2 + 0] = e0 * s;
        out[e * 2 + 1] = e1 * s;
    }
}

extern "C" void kernel_launch(void* const* d_in, const int* in_sizes, int n_in,
                              void* d_out, int out_size, void* d_ws, size_t ws_size,
                              hipStream_t stream) {
    const float* X  = (const float*)d_in[0];
    const float* H  = (const float*)d_in[1];
    const float* Wp = (const float*)d_in[2];
    const float* W0 = (const float*)d_in[3];
    const float* W1 = (const float*)d_in[4];
    const float* g0 = (const float*)d_in[5];
    const float* b0 = (const float*)d_in[6];
    const float* g1 = (const float*)d_in[7];
    const float* b1 = (const float*)d_in[8];
    const float* Wc = (const float*)d_in[9];
    const float* bc = (const float*)d_in[10];
    float* out = (float*)d_out;

    float* ws = (float*)d_ws;
    float* Xh  = ws + OFF_XH;
    unsigned short* Ub  = (unsigned short*)(ws + OFF_UB);
    unsigned short* Yb  = (unsigned short*)(ws + OFF_YB);
    int* node_cnt  = (int*)(ws + OFF_NCNT);
    int* edge_cnt  = (int*)(ws + OFF_ECNT);
    int* edge_list = (int*)(ws + OFF_EL);
    int* node_list = (int*)(ws + OFF_NL);
    unsigned short* Xhb = (unsigned short*)(ws + OFF_XHB);

    // node_cnt and edge_cnt are contiguous: one memset for both
    hipMemsetAsync(node_cnt, 0, (size_t)(NV + NE * 16) * sizeof(int), stream);

    // stage A: proj GEMM + fused U0 (blocks 0..255) + H scan; U0 hides under scan
    scan_proj<<<NPROJ + NSCAN, 256, 0, stream>>>(H, X, Wp, W0, Xh, Ub,
                                                 edge_cnt, node_cnt, edge_list, node_list);

    // layer 0
    edge_gather<<<NE, 64, 0, stream>>>(Ub, edge_cnt, edge_list, node_cnt, Yb);
    node_ln_u<<<NV / 32, 256, 0, stream>>>(Yb, node_cnt, node_list, edge_cnt,
                                           Xh, g0, b0, W1, Ub);   // fused U1 = LN-tile @ W1^T
    // layer 1
    edge_gather<<<NE, 64, 0, stream>>>(Ub, edge_cnt, edge_list, node_cnt, Yb);
    node_ln<<<NV, 64, 0, stream>>>(Yb, node_cnt, node_list, edge_cnt,
                                   Xh, Xhb, g1, b1);

    pool_classify<<<NE, 64, 0, stream>>>(Xhb, edge_cnt, edge_list, Wc, bc, out);
}

// Round 5
// 285.741 us; speedup vs baseline: 2.6702x; 1.0681x over previous
//
#include <hip/hip_runtime.h>
#include <math.h>

#define NV 8192
#define NE 4096
#define DIN 512
#define DH 256
#define CAP_E 96
#define CAP_V 64
#define NPROJ (NV / 32)      // 256 proj-GEMM blocks
#define NSCAN (NV / 2)       // 4096 scan blocks (4 waves/block, wave-per-half-row)

// ---------------- workspace layout (float offsets) ----------------
#define OFF_XH   0                       // V*DH fp32 (residual)
#define OFF_UB   (OFF_XH + NV*DH)        // V*DH bf16 (U = Xh@W^T)
#define OFF_YB   (OFF_UB + NV*DH/2)      // E*DH bf16
#define OFF_NCNT (OFF_YB + NE*DH/2)      // V ints
#define OFF_ECNT (OFF_NCNT + NV)         // E*16 ints (line-padded counters)
#define OFF_EL   (OFF_ECNT + NE*16)      // E*CAP_E ints
#define OFF_NL   (OFF_EL + NE*CAP_E)     // V*CAP_V ints
#define OFF_XHB  (OFF_NL + NV*CAP_V)     // V*DH bf16 (LN output bf16, feeds gemm_u / pool)

using bf16x8 = __attribute__((ext_vector_type(8))) short;
using f32x4  = __attribute__((ext_vector_type(4))) float;
using f32x4v = __attribute__((ext_vector_type(4))) float;

__device__ inline unsigned short f2bf(float f) {   // round-to-nearest-even
    union { float f; unsigned u; } v; v.f = f;
    unsigned r = v.u + 0x7FFF + ((v.u >> 16) & 1);
    return (unsigned short)(r >> 16);
}
__device__ inline float b2f(unsigned short s) {
    union { unsigned u; float f; } v; v.u = ((unsigned)s) << 16; return v.f;
}

// ---- U-GEMM from an LDS-stashed 32x256 bf16 A-tile: U = A @ W^T (bf16 out).
// Verified in round 4 (bit-identical to the standalone gemm_u path).
__device__ inline void u_gemm_from_lds(const short* __restrict__ sm,
                                       const float* __restrict__ W,
                                       unsigned short* __restrict__ Ub,
                                       int bm, int tid) {
    const int w = tid >> 6, lane = tid & 63;
    const int r15 = lane & 15, k8 = (lane >> 4) << 3;
    const int swz = lane ^ ((lane >> 3) & 6);
    f32x4 acc[2][4];
#pragma unroll
    for (int mi = 0; mi < 2; ++mi)
#pragma unroll
        for (int ni = 0; ni < 4; ++ni) acc[mi][ni] = (f32x4){0.f, 0.f, 0.f, 0.f};
#pragma unroll
    for (int kc = 0; kc < 8; ++kc) {
        bf16x8 af[2], bfr[4];
        af[0] = *(const bf16x8*)&sm[(0 * 8 + kc) * 512 + swz * 8];
        af[1] = *(const bf16x8*)&sm[(1 * 8 + kc) * 512 + swz * 8];
#pragma unroll
        for (int ni = 0; ni < 4; ++ni) {
            const float* wr = W + (size_t)(w * 64 + ni * 16 + r15) * DH + kc * 32 + k8;
            float4 b0 = *(const float4*)wr;
            float4 b1 = *(const float4*)(wr + 4);
            bf16x8 bv;
            bv[0] = (short)f2bf(b0.x); bv[1] = (short)f2bf(b0.y);
            bv[2] = (short)f2bf(b0.z); bv[3] = (short)f2bf(b0.w);
            bv[4] = (short)f2bf(b1.x); bv[5] = (short)f2bf(b1.y);
            bv[6] = (short)f2bf(b1.z); bv[7] = (short)f2bf(b1.w);
            bfr[ni] = bv;
        }
#pragma unroll
        for (int mi = 0; mi < 2; ++mi)
#pragma unroll
            for (int ni = 0; ni < 4; ++ni)
                acc[mi][ni] = __builtin_amdgcn_mfma_f32_16x16x32_bf16(
                    af[mi], bfr[ni], acc[mi][ni], 0, 0, 0);
    }
    const int quad = lane >> 4, cl = lane & 15;
#pragma unroll
    for (int mi = 0; mi < 2; ++mi)
#pragma unroll
        for (int ni = 0; ni < 4; ++ni)
#pragma unroll
            for (int r = 0; r < 4; ++r)
                Ub[(size_t)(bm + mi * 16 + quad * 4 + r) * DH + w * 64 + ni * 16 + cl]
                    = f2bf(acc[mi][ni][r]);
}

// ---- fused: blocks [0,NPROJ) proj GEMM Xh = X @ Wp^T (BK=32) + U0 = tile @ W0^T;
//      blocks [NPROJ, NPROJ+NSCAN): scan H, wave-per-half-row, batched atomics. ----
__global__ __launch_bounds__(256) void scan_proj(const float* __restrict__ H,
                                                 const float* __restrict__ X,
                                                 const float* __restrict__ Wp,
                                                 const float* __restrict__ W0,
                                                 float* __restrict__ Xh,
                                                 unsigned short* __restrict__ Ub,
                                                 int* __restrict__ edge_cnt,
                                                 int* __restrict__ node_cnt,
                                                 int* __restrict__ edge_list,
                                                 int* __restrict__ node_list) {
    __shared__ short AsBs[1024 + 8192];
    const int tid = threadIdx.x;
    if (blockIdx.x >= NPROJ) {
        const int w = tid >> 6, lane = tid & 63;
        const int v    = (blockIdx.x - NPROJ) * 2 + (w >> 1);
        const int half = w & 1;
        const f32x4v* H4 = (const f32x4v*)(H + (size_t)v * NE) + half * 512;
        f32x4v h[8];
#pragma unroll
        for (int it = 0; it < 8; ++it)
            h[it] = __builtin_nontemporal_load(&H4[lane + 64 * it]);  // 8 indep 1KB nt loads
        unsigned m = 0u;
#pragma unroll
        for (int it = 0; it < 8; ++it) {
#pragma unroll
            for (int c = 0; c < 4; ++c)
                m |= (h[it][c] != 0.0f ? 1u : 0u) << (it * 4 + c);
        }
        int n = __builtin_popcount(m);
        int pre = n;
#pragma unroll
        for (int o = 1; o < 64; o <<= 1) {
            int t = __shfl_up(pre, o, 64);
            if (lane >= o) pre += t;
        }
        int total = __shfl(pre, 63, 64);
        int local = pre - n;
        int base = 0;
        if (lane == 0 && total > 0) base = atomicAdd(&node_cnt[v], total);
        base = __shfl(base, 0, 64) + local;
        const int ebase = half * 2048 + 4 * lane;
        int e_arr[4] = {0, 0, 0, 0};
        {
            unsigned mm = m;
#pragma unroll
            for (int u = 0; u < 4; ++u) {
                if (mm) {
                    int j = __builtin_ctz(mm);
                    mm &= mm - 1;
                    e_arr[u] = ebase + 256 * (j >> 2) + (j & 3);
                }
            }
        }
        int s_arr[4];
#pragma unroll
        for (int u = 0; u < 4; ++u)
            s_arr[u] = (u < n) ? atomicAdd(&edge_cnt[e_arr[u] << 4], 1) : 0;
#pragma unroll
        for (int u = 0; u < 4; ++u) {
            if (u < n) {
                if (s_arr[u] < CAP_E) edge_list[e_arr[u] * CAP_E + s_arr[u]] = v;
                int idx = base + u;
                if (idx < CAP_V) node_list[v * CAP_V + idx] = e_arr[u];
            }
        }
        if (n > 4) {
            unsigned mm = m;
            mm &= mm - 1; mm &= mm - 1; mm &= mm - 1; mm &= mm - 1;
            int k = 4;
            while (mm) {
                int j = __builtin_ctz(mm); mm &= mm - 1;
                int ee = ebase + 256 * (j >> 2) + (j & 3);
                int gc = atomicAdd(&edge_cnt[ee << 4], 1);
                if (gc < CAP_E) edge_list[ee * CAP_E + gc] = v;
                int idx = base + k;
                if (idx < CAP_V) node_list[v * CAP_V + idx] = ee;
                ++k;
            }
        }
        return;
    }
    // ---------------- proj GEMM path: BM=32, BN=256, BK=32, K=DIN ----------------
    short* As = AsBs;
    short* Bs = AsBs + 1024;
    const int K = DIN;
    const int lane = tid & 63;
    const int w    = tid >> 6;
    const int bm   = blockIdx.x * 32;
    const int swz  = lane ^ ((lane >> 3) & 6);
    float4 ar, br[8];
    ar = *(const float4*)(X + (size_t)(bm + (tid >> 3)) * K + ((tid & 7) << 2));
#pragma unroll
    for (int it = 0; it < 8; ++it) {
        int i = tid + it * 256;
        br[it] = *(const float4*)(Wp + (size_t)(i >> 3) * K + ((i & 7) << 2));
    }
    f32x4 acc[2][4];
#pragma unroll
    for (int mi = 0; mi < 2; ++mi)
#pragma unroll
        for (int ni = 0; ni < 4; ++ni) acc[mi][ni] = (f32x4){0.f, 0.f, 0.f, 0.f};
    for (int k0 = 0; k0 < K; k0 += 32) {
        __syncthreads();
        {
            int row = tid >> 3, kk = (tid & 7) << 2;
            int quad = kk >> 3, j = kk & 7;
            int ln = (row & 15) + (quad << 4);
            int pp = ln ^ ((ln >> 3) & 6);
            ushort4 u = {f2bf(ar.x), f2bf(ar.y), f2bf(ar.z), f2bf(ar.w)};
            *(ushort4*)&As[(row >> 4) * 512 + pp * 8 + j] = u;
        }
#pragma unroll
        for (int it = 0; it < 8; ++it) {
            int i = tid + it * 256;
            int row = i >> 3, kk = (i & 7) << 2;
            int quad = kk >> 3, j = kk & 7;
            int ln = (row & 15) + (quad << 4);
            int pp = ln ^ ((ln >> 3) & 6);
            float4 v = br[it];
            ushort4 u = {f2bf(v.x), f2bf(v.y), f2bf(v.z), f2bf(v.w)};
            *(ushort4*)&Bs[(row >> 4) * 512 + pp * 8 + j] = u;
        }
        __syncthreads();
        if (k0 + 32 < K) {
            int kn = k0 + 32;
            ar = *(const float4*)(X + (size_t)(bm + (tid >> 3)) * K + kn + ((tid & 7) << 2));
#pragma unroll
            for (int it = 0; it < 8; ++it) {
                int i = tid + it * 256;
                br[it] = *(const float4*)(Wp + (size_t)(i >> 3) * K + kn + ((i & 7) << 2));
            }
        }
        bf16x8 af[2], bfr[4];
        af[0] = *(const bf16x8*)&As[0 * 512 + swz * 8];
        af[1] = *(const bf16x8*)&As[1 * 512 + swz * 8];
#pragma unroll
        for (int ni = 0; ni < 4; ++ni)
            bfr[ni] = *(const bf16x8*)&Bs[(w * 4 + ni) * 512 + swz * 8];
#pragma unroll
        for (int mi = 0; mi < 2; ++mi)
#pragma unroll
            for (int ni = 0; ni < 4; ++ni)
                acc[mi][ni] = __builtin_amdgcn_mfma_f32_16x16x32_bf16(
                    af[mi], bfr[ni], acc[mi][ni], 0, 0, 0);
    }
    const int quad = lane >> 4, cl = lane & 15;
    __syncthreads();   // all waves done reading As/Bs before the U-stash reuses LDS
#pragma unroll
    for (int mi = 0; mi < 2; ++mi)
#pragma unroll
        for (int ni = 0; ni < 4; ++ni)
#pragma unroll
            for (int r = 0; r < 4; ++r) {
                float v = acc[mi][ni][r];
                int rl  = mi * 16 + quad * 4 + r;
                int col = w * 64 + ni * 16 + cl;
                Xh[(size_t)(bm + rl) * DH + col] = v;
                // stash bf16 into MFMA-ready swizzled A-tile for the fused U0-GEMM
                int kc = col >> 5, kk = col & 31;
                int q2 = kk >> 3, j = kk & 7;
                int ln = (rl & 15) + (q2 << 4);
                int pp = ln ^ ((ln >> 3) & 6);
                AsBs[(mi * 8 + kc) * 512 + pp * 8 + j] = (short)f2bf(v);
            }
    __syncthreads();
    u_gemm_from_lds(AsBs, W0, Ub, bm, tid);
}

// ------- U = bf16(Xhb @ W^T): bf16 A (no conversion), K=256, BM=32 (round-0 verbatim) ----
__global__ __launch_bounds__(256) void gemm_u(const unsigned short* __restrict__ A,
                                              const float* __restrict__ W,
                                              unsigned short* __restrict__ U) {
    const int K = DH;
    __shared__ short As[2048];
    __shared__ short Bs[16384];
    const int tid  = threadIdx.x;
    const int lane = tid & 63;
    const int w    = tid >> 6;
    const int bm   = blockIdx.x * 32;
    const int swz  = lane ^ ((lane >> 3) & 6);

    uint4 ar; float4 br[16];
    ar = *(const uint4*)(A + (size_t)(bm + (tid >> 3)) * K + ((tid & 7) << 3));
#pragma unroll
    for (int it = 0; it < 16; ++it) {
        int i = tid + it * 256;
        br[it] = *(const float4*)(W + (size_t)(i >> 4) * K + ((i & 15) << 2));
    }
    f32x4 acc[2][4];
#pragma unroll
    for (int mi = 0; mi < 2; ++mi)
#pragma unroll
        for (int ni = 0; ni < 4; ++ni) acc[mi][ni] = (f32x4){0.f, 0.f, 0.f, 0.f};

    for (int k0 = 0; k0 < K; k0 += 64) {
        __syncthreads();
        {
            int row = tid >> 3, kq = tid & 7;
            int kc = kq >> 2, quad = kq & 3;
            int ln = (row & 15) + (quad << 4);
            int pp = ln ^ ((ln >> 3) & 6);
            *(uint4*)&As[((row >> 4) * 2 + kc) * 512 + pp * 8] = ar;
        }
#pragma unroll
        for (int it = 0; it < 16; ++it) {
            int i = tid + it * 256;
            int row = i >> 4, kk = (i & 15) << 2;
            int kc = kk >> 5, quad = (kk >> 3) & 3, j = kk & 7;
            int ln = (row & 15) + (quad << 4);
            int pp = ln ^ ((ln >> 3) & 6);
            float4 v = br[it];
            ushort4 u = {f2bf(v.x), f2bf(v.y), f2bf(v.z), f2bf(v.w)};
            *(ushort4*)&Bs[((row >> 4) * 2 + kc) * 512 + pp * 8 + j] = u;
        }
        __syncthreads();
        if (k0 + 64 < K) {
            int kn = k0 + 64;
            ar = *(const uint4*)(A + (size_t)(bm + (tid >> 3)) * K + kn + ((tid & 7) << 3));
#pragma unroll
            for (int it = 0; it < 16; ++it) {
                int i = tid + it * 256;
                br[it] = *(const float4*)(W + (size_t)(i >> 4) * K + kn + ((i & 15) << 2));
            }
        }
#pragma unroll
        for (int kc = 0; kc < 2; ++kc) {
            bf16x8 af[2], bfr[4];
            af[0] = *(const bf16x8*)&As[(0 * 2 + kc) * 512 + swz * 8];
            af[1] = *(const bf16x8*)&As[(1 * 2 + kc) * 512 + swz * 8];
#pragma unroll
            for (int ni = 0; ni < 4; ++ni)
                bfr[ni] = *(const bf16x8*)&Bs[((w * 4 + ni) * 2 + kc) * 512 + swz * 8];
#pragma unroll
            for (int mi = 0; mi < 2; ++mi)
#pragma unroll
                for (int ni = 0; ni < 4; ++ni)
                    acc[mi][ni] = __builtin_amdgcn_mfma_f32_16x16x32_bf16(
                        af[mi], bfr[ni], acc[mi][ni], 0, 0, 0);
        }
    }
    const int quad = lane >> 4, cl = lane & 15;
#pragma unroll
    for (int mi = 0; mi < 2; ++mi)
#pragma unroll
        for (int ni = 0; ni < 4; ++ni)
#pragma unroll
            for (int r = 0; r < 4; ++r)
                U[(size_t)(bm + mi * 16 + quad * 4 + r) * DH + w * 64 + ni * 16 + cl]
                    = f2bf(acc[mi][ni][r]);
}

// ---- Yb[e,:] = bf16( rsqrt(de) * sum_{v in e} rsqrt(dv) * Ub[v,:] ) ----
__global__ __launch_bounds__(64) void edge_gather(const unsigned short* __restrict__ Ub,
                                                  const int* __restrict__ edge_cnt,
                                                  const int* __restrict__ edge_list,
                                                  const int* __restrict__ node_cnt,
                                                  unsigned short* __restrict__ Yb) {
    int e = blockIdx.x;
    int tid = threadIdx.x;
    __shared__ int   lv[CAP_E];
    __shared__ float lc[CAP_E];
    int tc = edge_cnt[e << 4];
    int cnt = min(tc, CAP_E);
    for (int j = tid; j < cnt; j += 64) {
        int v = edge_list[e * CAP_E + j];
        lv[j] = v * (DH / 4);
        lc[j] = rsqrtf((float)node_cnt[v]);
    }
    __syncthreads();
    const ushort4* X4 = (const ushort4*)Ub;
    float4 a[8];
#pragma unroll
    for (int u = 0; u < 8; ++u) a[u] = (float4){0.f, 0.f, 0.f, 0.f};
    int i = 0;
    for (; i + 8 <= cnt; i += 8) {
#pragma unroll
        for (int u = 0; u < 8; ++u) {
            ushort4 h = X4[lv[i + u] + tid]; float c = lc[i + u];
            a[u].x = fmaf(c, b2f(h.x), a[u].x); a[u].y = fmaf(c, b2f(h.y), a[u].y);
            a[u].z = fmaf(c, b2f(h.z), a[u].z); a[u].w = fmaf(c, b2f(h.w), a[u].w);
        }
    }
    for (; i < cnt; ++i) {
        ushort4 h = X4[lv[i] + tid]; float c = lc[i];
        a[0].x = fmaf(c, b2f(h.x), a[0].x); a[0].y = fmaf(c, b2f(h.y), a[0].y);
        a[0].z = fmaf(c, b2f(h.z), a[0].z); a[0].w = fmaf(c, b2f(h.w), a[0].w);
    }
#pragma unroll
    for (int u = 4; u > 0; u >>= 1)
#pragma unroll
        for (int q = 0; q < u; ++q) {
            a[q].x += a[q + u].x; a[q].y += a[q + u].y;
            a[q].z += a[q + u].z; a[q].w += a[q + u].w;
        }
    float de = tc > 0 ? rsqrtf((float)tc) : 0.f;
    ushort4 o = {f2bf(de * a[0].x), f2bf(de * a[0].y),
                 f2bf(de * a[0].z), f2bf(de * a[0].w)};
    ((ushort4*)Yb)[e * (DH / 4) + tid] = o;
}

// ---- node gather + relu + residual + LayerNorm, one wave per row (round-0 verbatim) ----
__global__ __launch_bounds__(64) void node_ln(const unsigned short* __restrict__ Yb,
                                              const int* __restrict__ node_cnt,
                                              const int* __restrict__ node_list,
                                              const int* __restrict__ edge_cnt,
                                              float* __restrict__ Xh,
                                              unsigned short* __restrict__ Xhb,
                                              const float* __restrict__ g,
                                              const float* __restrict__ b) {
    int v = blockIdx.x;
    int tid = threadIdx.x;
    __shared__ int   le[CAP_V];
    __shared__ float lc[CAP_V];
    int tc = node_cnt[v];
    int cnt = min(tc, CAP_V);
    if (tid < cnt) {
        int e = node_list[v * CAP_V + tid];
        le[tid] = e * (DH / 4);
        lc[tid] = rsqrtf((float)edge_cnt[e << 4]);
    }
    __syncthreads();
    const ushort4* Y4 = (const ushort4*)Yb;
    float4 a[8];
#pragma unroll
    for (int u = 0; u < 8; ++u) a[u] = (float4){0.f, 0.f, 0.f, 0.f};
    int i = 0;
    for (; i + 8 <= cnt; i += 8) {
#pragma unroll
        for (int u = 0; u < 8; ++u) {
            ushort4 h = Y4[le[i + u] + tid]; float c = lc[i + u];
            a[u].x = fmaf(c, b2f(h.x), a[u].x); a[u].y = fmaf(c, b2f(h.y), a[u].y);
            a[u].z = fmaf(c, b2f(h.z), a[u].z); a[u].w = fmaf(c, b2f(h.w), a[u].w);
        }
    }
    for (; i < cnt; ++i) {
        ushort4 h = Y4[le[i] + tid]; float c = lc[i];
        a[0].x = fmaf(c, b2f(h.x), a[0].x); a[0].y = fmaf(c, b2f(h.y), a[0].y);
        a[0].z = fmaf(c, b2f(h.z), a[0].z); a[0].w = fmaf(c, b2f(h.w), a[0].w);
    }
#pragma unroll
    for (int u = 4; u > 0; u >>= 1)
#pragma unroll
        for (int q = 0; q < u; ++q) {
            a[q].x += a[q + u].x; a[q].y += a[q + u].y;
            a[q].z += a[q + u].z; a[q].w += a[q + u].w;
        }
    float dv = tc > 0 ? rsqrtf((float)tc) : 0.f;
    float4 xr = ((const float4*)Xh)[v * (DH / 4) + tid];
    float x0 = xr.x + fmaxf(dv * a[0].x, 0.f);
    float x1 = xr.y + fmaxf(dv * a[0].y, 0.f);
    float x2 = xr.z + fmaxf(dv * a[0].z, 0.f);
    float x3 = xr.w + fmaxf(dv * a[0].w, 0.f);
    float s = (x0 + x1) + (x2 + x3);
    float q = fmaf(x0, x0, fmaf(x1, x1, fmaf(x2, x2, x3 * x3)));
#pragma unroll
    for (int o = 1; o < 64; o <<= 1) {
        s += __shfl_xor(s, o, 64);
        q += __shfl_xor(q, o, 64);
    }
    float m = s * (1.0f / DH);
    float var = q * (1.0f / DH) - m * m;
    float rstd = rsqrtf(var + 1e-5f);
    float4 g4 = ((const float4*)g)[tid];
    float4 b4 = ((const float4*)b)[tid];
    float4 o;
    o.x = (x0 - m) * rstd * g4.x + b4.x;
    o.y = (x1 - m) * rstd * g4.y + b4.y;
    o.z = (x2 - m) * rstd * g4.z + b4.z;
    o.w = (x3 - m) * rstd * g4.w + b4.w;
    ((float4*)Xh)[v * (DH / 4) + tid] = o;
    ushort4 ob = {f2bf(o.x), f2bf(o.y), f2bf(o.z), f2bf(o.w)};
    ((ushort4*)Xhb)[v * (DH / 4) + tid] = ob;
}

// ------- fused mean-pool + classifier + softmax (64 thr, bf16 src) -------
__global__ __launch_bounds__(64) void pool_classify(const unsigned short* __restrict__ Xhb,
                                                    const int* __restrict__ edge_cnt,
                                                    const int* __restrict__ edge_list,
                                                    const float* __restrict__ Wc,
                                                    const float* __restrict__ bc,
                                                    float* __restrict__ out) {
    int e = blockIdx.x;
    int tid = threadIdx.x;
    __shared__ int lv[CAP_E];
    int tc = edge_cnt[e << 4];
    int cnt = min(tc, CAP_E);
    for (int j = tid; j < cnt; j += 64) lv[j] = edge_list[e * CAP_E + j] * (DH / 4);
    __syncthreads();
    const ushort4* X4 = (const ushort4*)Xhb;
    float4 a[8];
#pragma unroll
    for (int u = 0; u < 8; ++u) a[u] = (float4){0, 0, 0, 0};
    int i = 0;
    for (; i + 8 <= cnt; i += 8) {
#pragma unroll
        for (int u = 0; u < 8; ++u) {
            ushort4 h = X4[lv[i + u] + tid];
            a[u].x += b2f(h.x); a[u].y += b2f(h.y);
            a[u].z += b2f(h.z); a[u].w += b2f(h.w);
        }
    }
    for (; i < cnt; ++i) {
        ushort4 h = X4[lv[i] + tid];
        a[0].x += b2f(h.x); a[0].y += b2f(h.y);
        a[0].z += b2f(h.z); a[0].w += b2f(h.w);
    }
#pragma unroll
    for (int u = 4; u > 0; u >>= 1)
#pragma unroll
        for (int q = 0; q < u; ++q) {
            a[q].x += a[q + u].x; a[q].y += a[q + u].y;
            a[q].z += a[q + u].z; a[q].w += a[q + u].w;
        }
    float inv = tc > 0 ? 1.0f / (float)tc : 1.0f;
    float4 val = {a[0].x * inv, a[0].y * inv, a[0].z * inv, a[0].w * inv};
    const float4* W4 = (const float4*)Wc;
    float4 w0 = W4[tid], w1 = W4[64 + tid];
    float p0 = val.x * w0.x + val.y * w0.y + val.z * w0.z + val.w * w0.w;
    float p1 = val.x * w1.x + val.y * w1.y + val.z * w1.z + val.w * w1.w;
#pragma unroll
    for (int o = 32; o > 0; o >>= 1) {
        p0 += __shfl_down(p0, o, 64);
        p1 += __shfl_down(p1, o, 64);
    }
    if (tid == 0) {
        float l0 = p0 + bc[0], l1 = p1 + bc[1];
        float mx = fmaxf(l0, l1);
        float e0 = expf(l0 - mx), e1 = expf(l1 - mx);
        float s = 1.0f / (e0 + e1);
        out[e * 2 + 0] = e0 * s;
        out[e * 2 + 1] = e1 * s;
    }
}

extern "C" void kernel_launch(void* const* d_in, const int* in_sizes, int n_in,
                              void* d_out, int out_size, void* d_ws, size_t ws_size,
                              hipStream_t stream) {
    const float* X  = (const float*)d_in[0];
    const float* H  = (const float*)d_in[1];
    const float* Wp = (const float*)d_in[2];
    const float* W0 = (const float*)d_in[3];
    const float* W1 = (const float*)d_in[4];
    const float* g0 = (const float*)d_in[5];
    const float* b0 = (const float*)d_in[6];
    const float* g1 = (const float*)d_in[7];
    const float* b1 = (const float*)d_in[8];
    const float* Wc = (const float*)d_in[9];
    const float* bc = (const float*)d_in[10];
    float* out = (float*)d_out;

    float* ws = (float*)d_ws;
    float* Xh  = ws + OFF_XH;
    unsigned short* Ub  = (unsigned short*)(ws + OFF_UB);
    unsigned short* Yb  = (unsigned short*)(ws + OFF_YB);
    int* node_cnt  = (int*)(ws + OFF_NCNT);
    int* edge_cnt  = (int*)(ws + OFF_ECNT);
    int* edge_list = (int*)(ws + OFF_EL);
    int* node_list = (int*)(ws + OFF_NL);
    unsigned short* Xhb = (unsigned short*)(ws + OFF_XHB);

    // node_cnt and edge_cnt are contiguous: one memset for both
    hipMemsetAsync(node_cnt, 0, (size_t)(NV + NE * 16) * sizeof(int), stream);

    // stage A: proj GEMM + fused U0 (blocks 0..255, hides under the 4096-block scan)
    scan_proj<<<NPROJ + NSCAN, 256, 0, stream>>>(H, X, Wp, W0, Xh, Ub,
                                                 edge_cnt, node_cnt, edge_list, node_list);

    // layer 0 (U0 already in Ub)
    edge_gather<<<NE, 64, 0, stream>>>(Ub, edge_cnt, edge_list, node_cnt, Yb);
    node_ln<<<NV, 64, 0, stream>>>(Yb, node_cnt, node_list, edge_cnt,
                                   Xh, Xhb, g0, b0);
    // layer 1 (U1 from standalone high-occupancy gemm_u)
    gemm_u<<<NV / 32, 256, 0, stream>>>(Xhb, W1, Ub);
    edge_gather<<<NE, 64, 0, stream>>>(Ub, edge_cnt, edge_list, node_cnt, Yb);
    node_ln<<<NV, 64, 0, stream>>>(Yb, node_cnt, node_list, edge_cnt,
                                   Xh, Xhb, g1, b1);

    pool_classify<<<NE, 64, 0, stream>>>(Xhb, edge_cnt, edge_list, Wc, bc, out);
}